// Round 11
// baseline (136.542 us; speedup 1.0000x reference)
//
#include <hip/hip_runtime.h>

typedef _Float16 f16;
typedef __attribute__((ext_vector_type(8))) _Float16 f16x8;
typedef __attribute__((ext_vector_type(4))) _Float16 f16x4;
typedef __attribute__((ext_vector_type(4))) float f32x4;
typedef __attribute__((ext_vector_type(16))) float f32x16;
typedef __attribute__((ext_vector_type(2))) unsigned int u32x2;
typedef __attribute__((ext_vector_type(4))) unsigned int u32x4;

#define B_ 4
#define N_ 2048
#define DIM_ 512
#define H_ 8
#define DH_ 64

// global -> LDS direct (16B per lane). LDS dest must be wave-uniform;
// global src is per-lane (pre-swizzled). Size must be literal 16.
__device__ __forceinline__ void gload16(const void* g, void* l) {
    __builtin_amdgcn_global_load_lds((const __attribute__((address_space(1))) void*)g,
                                     (__attribute__((address_space(3))) void*)l, 16, 0, 0);
}

// ---------------- small conversion kernels ----------------

__global__ __launch_bounds__(256) void cvt_f16_k8(const float* __restrict__ in,
                                                  f16* __restrict__ out, int n8) {
    int i = blockIdx.x * 256 + threadIdx.x;
    if (i < n8) {
        const float4 a = ((const float4*)in)[i * 2];
        const float4 b = ((const float4*)in)[i * 2 + 1];
        f16x8 o = {(f16)a.x, (f16)a.y, (f16)a.z, (f16)a.w,
                   (f16)b.x, (f16)b.y, (f16)b.z, (f16)b.w};
        ((f16x8*)out)[i] = o;
    }
}

// out[n*K + k] = (f16) in[k*N + n]; LDS-tiled 64x64, coalesced on both sides.
__global__ __launch_bounds__(256) void transpose_cvt_k(const float* __restrict__ in,
                                                       f16* __restrict__ out, int K, int N) {
    __shared__ f16 tile[64][72];            // [n][k], +8 pad
    const int nbk = K >> 6;
    const int bk = blockIdx.x % nbk, bn = blockIdx.x / nbk;
    const int k0 = bk << 6, n0 = bn << 6;
    const int t = threadIdx.x;
    const int r = t >> 2, q = (t & 3) << 4;
#pragma unroll
    for (int u = 0; u < 4; u++) {
        const float4 v = *(const float4*)&in[(size_t)(k0 + r) * N + n0 + q + u * 4];
        tile[q + u * 4 + 0][r] = (f16)v.x;
        tile[q + u * 4 + 1][r] = (f16)v.y;
        tile[q + u * 4 + 2][r] = (f16)v.z;
        tile[q + u * 4 + 3][r] = (f16)v.w;
    }
    __syncthreads();
#pragma unroll
    for (int u = 0; u < 2; u++) {
        f16x8 o = *(const f16x8*)&tile[r][q + u * 8];
        *(f16x8*)&out[(size_t)(n0 + r) * K + k0 + q + u * 8] = o;
    }
}

// ---------------- GEMM: C = A[M][K] * BT[N][K]^T (m97 structure) ----------------
template <int EPI>
__global__ __launch_bounds__(256) void gemm_bt(
    const f16* __restrict__ A, const f16* __restrict__ BT, int K, int N,
    f16* __restrict__ qb, f16* __restrict__ kb, f16* __restrict__ vbT,
    float* __restrict__ vsb, const float* __restrict__ bias, float* __restrict__ outp)
{
    __shared__ char sAb[16384];   // [128 m][64 k] f16, swizzled
    __shared__ char sBb[16384];   // [128 n][64 k] f16, swizzled
    const int tid = threadIdx.x;
    const int m0 = blockIdx.y * 128, n0 = blockIdx.x * 128;
    const int wave = tid >> 6, lane = tid & 63;
    const int wr = wave >> 1, wc = wave & 1;
    const int lr = lane & 15, lg = lane >> 4;

    f32x4 acc[4][4];
    const f32x4 zero = {0.f, 0.f, 0.f, 0.f};
#pragma unroll
    for (int i = 0; i < 4; i++)
#pragma unroll
        for (int j = 0; j < 4; j++) acc[i][j] = zero;

    const f16* srcA[4]; const f16* srcB[4];
    char* ldsA[4]; char* ldsB[4];
#pragma unroll
    for (int u = 0; u < 4; u++) {
        int row = wave * 8 + u * 32 + (lane >> 3);
        int e0 = ((lane & 7) ^ (row & 7)) << 3;
        srcA[u] = A + (size_t)(m0 + row) * K + e0;
        srcB[u] = BT + (size_t)(n0 + row) * K + e0;
        ldsA[u] = sAb + wave * 1024 + u * 4096;
        ldsB[u] = sBb + wave * 1024 + u * 4096;
    }

    const int swz = (lr & 7) << 4;
    for (int kt = 0; kt < K; kt += 64) {
#pragma unroll
        for (int u = 0; u < 4; u++) {
            gload16(srcA[u], ldsA[u]);
            gload16(srcB[u], ldsB[u]);
            srcA[u] += 64; srcB[u] += 64;
        }
        __syncthreads();
#pragma unroll
        for (int half = 0; half < 2; half++) {
            f16x8 af[4], bf[4];
#pragma unroll
            for (int i = 0; i < 4; i++) {
                int R = wr * 64 + i * 16 + lr;
                af[i] = *(const f16x8*)(sAb + R * 128 + (((half << 6) | (lg << 4)) ^ swz));
            }
#pragma unroll
            for (int j = 0; j < 4; j++) {
                int R = wc * 64 + j * 16 + lr;
                bf[j] = *(const f16x8*)(sBb + R * 128 + (((half << 6) | (lg << 4)) ^ swz));
            }
#pragma unroll
            for (int i = 0; i < 4; i++)
#pragma unroll
                for (int j = 0; j < 4; j++)
                    acc[i][j] = __builtin_amdgcn_mfma_f32_16x16x32_f16(af[i], bf[j], acc[i][j], 0, 0, 0);
        }
        __syncthreads();
    }

#pragma unroll
    for (int i = 0; i < 4; i++) {
#pragma unroll
        for (int j = 0; j < 4; j++) {
            int col = n0 + wc * 64 + j * 16 + lr;
            int row0 = m0 + wr * 64 + i * 16 + lg * 4;
            if (EPI == 0) {
                int sec = col >> 9, cc = col & 511;
                int h = cc >> 6, d = cc & 63;
                int b = row0 >> 11, ns = row0 & 2047;
                if (sec == 2) {
                    f16x4 o;
#pragma unroll
                    for (int r = 0; r < 4; r++) o[r] = (f16)acc[i][j][r];
                    *(f16x4*)&vbT[((size_t)(b * H_ + h) * DH_ + d) * N_ + ns] = o;
                } else if (sec == 0) {
#pragma unroll
                    for (int r = 0; r < 4; r++)
                        qb[((size_t)(b * H_ + h) * N_ + ns + r) * DH_ + d] = (f16)(acc[i][j][r] * 0.1803368801f);
                } else if (sec == 1) {
#pragma unroll
                    for (int r = 0; r < 4; r++)
                        kb[((size_t)(b * H_ + h) * N_ + ns + r) * DH_ + d] = (f16)acc[i][j][r];
                } else {
#pragma unroll
                    for (int r = 0; r < 4; r++)
                        vsb[((size_t)(b * H_ + h) * N_ + ns + r) * DH_ + d] = acc[i][j][r];
                }
            } else {
#pragma unroll
                for (int r = 0; r < 4; r++)
                    outp[(size_t)(row0 + r) * N + col] = acc[i][j][r] + bias[col];
            }
        }
    }
}

// ---------------- small-N GEMM (final projection): 64x64 tile ----------------
__global__ __launch_bounds__(256) void gemm_small(
    const f16* __restrict__ A, const f16* __restrict__ BT, int K, int N,
    const float* __restrict__ bias, float* __restrict__ outp)
{
    __shared__ char sAb[8192];
    __shared__ char sBb[8192];
    const int tid = threadIdx.x;
    const int m0 = blockIdx.y * 64, n0 = blockIdx.x * 64;
    const int wave = tid >> 6, lane = tid & 63;
    const int wr = wave >> 1, wc = wave & 1;
    const int lr = lane & 15, lg = lane >> 4;

    f32x4 acc[2][2];
    const f32x4 zero = {0.f, 0.f, 0.f, 0.f};
#pragma unroll
    for (int i = 0; i < 2; i++)
#pragma unroll
        for (int j = 0; j < 2; j++) acc[i][j] = zero;

    const f16* srcA[2]; const f16* srcB[2];
    char* ldsA[2]; char* ldsB[2];
#pragma unroll
    for (int u = 0; u < 2; u++) {
        int row = wave * 8 + u * 32 + (lane >> 3);
        int e0 = ((lane & 7) ^ (row & 7)) << 3;
        srcA[u] = A + (size_t)(m0 + row) * K + e0;
        srcB[u] = BT + (size_t)(n0 + row) * K + e0;
        ldsA[u] = sAb + wave * 1024 + u * 4096;
        ldsB[u] = sBb + wave * 1024 + u * 4096;
    }

    const int swz = (lr & 7) << 4;
    for (int kt = 0; kt < K; kt += 64) {
#pragma unroll
        for (int u = 0; u < 2; u++) {
            gload16(srcA[u], ldsA[u]);
            gload16(srcB[u], ldsB[u]);
            srcA[u] += 64; srcB[u] += 64;
        }
        __syncthreads();
#pragma unroll
        for (int half = 0; half < 2; half++) {
            f16x8 af[2], bf[2];
#pragma unroll
            for (int i = 0; i < 2; i++) {
                int R = wr * 32 + i * 16 + lr;
                af[i] = *(const f16x8*)(sAb + R * 128 + (((half << 6) | (lg << 4)) ^ swz));
            }
#pragma unroll
            for (int j = 0; j < 2; j++) {
                int R = wc * 32 + j * 16 + lr;
                bf[j] = *(const f16x8*)(sBb + R * 128 + (((half << 6) | (lg << 4)) ^ swz));
            }
#pragma unroll
            for (int i = 0; i < 2; i++)
#pragma unroll
                for (int j = 0; j < 2; j++)
                    acc[i][j] = __builtin_amdgcn_mfma_f32_16x16x32_f16(af[i], bf[j], acc[i][j], 0, 0, 0);
        }
        __syncthreads();
    }

#pragma unroll
    for (int i = 0; i < 2; i++)
#pragma unroll
        for (int j = 0; j < 2; j++) {
            int col = n0 + wc * 32 + j * 16 + lr;
            int row0 = m0 + wr * 32 + i * 16 + lg * 4;
#pragma unroll
            for (int r = 0; r < 4; r++)
                outp[(size_t)(row0 + r) * N + col] = acc[i][j][r] + bias[col];
        }
}

// ---------------- flash attention (softmax branch), 32x32 MFMA ----------------
// grid = 512 flat, XCD-swizzled. Block = 128 q: 4 waves x 32 q (q = lane&31,
// hh = lane>>5 indexes dh/kv halves). R9 showed the kernel is MFMA-ISSUE-bound
// (56 issues/wave/tile, 40 of them K=16 at half FLOPs); this restructure does
// the same math in 16 issues of 32x32x16 (QK 8 + PV 8), l-sum on VALU.
// St C-layout: lane holds St[kv=8*(r>>2)+4*hh+(r&3)][q=lane&31]. PV B-frag
// needs P[kv=16c+8*hh+j][q]: Blo=[Q2c.lo|Q2c1.lo], Bhi=[Q2c.hi|Q2c1.hi]
// built via shfl_xor(32) + select. Static max (m=0, R7 analysis). Pipeline,
// staging, swizzle = R8's (K 3-buf, V 2-buf, counted vmcnt(6)).
__global__ __launch_bounds__(256) void attn_k(
    const f16* __restrict__ qb, const f16* __restrict__ kb, const f16* __restrict__ vbT,
    f16* __restrict__ cat)
{
    __shared__ char sKbf[3 * 8192];   // K bufs, [64 kv][64 dh] f16, swizzled
    __shared__ char sVbf[2 * 8192];   // V bufs, [64 d ][64 kv] f16, swizzled
    const int tid = threadIdx.x;
    const int bid0 = blockIdx.x;
    const int obid = (bid0 & 7) * 64 + (bid0 >> 3);    // bijective XCD swizzle (512 = 8*64)
    const int bh = obid >> 4, qblk = obid & 15;
    const int b = bh >> 3, h_head = bh & 7;
    const int wave = tid >> 6, lane = tid & 63;
    const int l31 = lane & 31, hh = lane >> 5;

    const size_t base = (size_t)bh * N_ * DH_;
    const int qrow = qblk * 128 + wave * 32 + l31;
    f16x8 qf[4];                      // Q B-frags: k = c*16 + hh*8 + j
#pragma unroll
    for (int c = 0; c < 4; c++)
        qf[c] = *(const f16x8*)&qb[base + (size_t)qrow * DH_ + c * 16 + hh * 8];

    // staging (identical to R8/R9): round u covers rows wave*8+u*32+(lane>>3)
    const f16* kq[2]; const f16* vq[2];
#pragma unroll
    for (int u = 0; u < 2; u++) {
        int row = wave * 8 + u * 32 + (lane >> 3);
        int e0 = ((lane & 7) ^ (row & 7)) << 3;
        kq[u] = kb + base + (size_t)row * 64 + e0;
        vq[u] = vbT + base + (size_t)row * 2048 + e0;
    }
    char* const ldsKw = sKbf + wave * 1024;
    char* const ldsVw = sVbf + wave * 1024;

    f32x16 Ot0 = 0.f, Ot1 = 0.f;      // d-tiles 0..31, 32..63
    float l_run = 0.f;

    const int swz = (lane & 7) << 4;

    // prologue: K(0), V(0), K(1)
#pragma unroll
    for (int u = 0; u < 2; u++) gload16(kq[u], ldsKw + u * 4096);
#pragma unroll
    for (int u = 0; u < 2; u++) gload16(vq[u], ldsVw + u * 4096);
#pragma unroll
    for (int u = 0; u < 2; u++) gload16(kq[u] + 4096, ldsKw + 8192 + u * 4096);

    int kcur = 0, kpre = 2;
    for (int t = 0; t < 32; t++) {
        __builtin_amdgcn_s_barrier();
        {   // issue V(t+1) then K(t+2), wrapped mod 32
            const int vtn = (t + 1) & 31, ktn = (t + 2) & 31;
            char* vdst = ldsVw + ((t + 1) & 1) * 8192;
            char* kdst = ldsKw + kpre * 8192;
#pragma unroll
            for (int u = 0; u < 2; u++) gload16(vq[u] + vtn * 64, vdst + u * 4096);
#pragma unroll
            for (int u = 0; u < 2; u++) gload16(kq[u] + ktn * 4096, kdst + u * 4096);
        }
        asm volatile("s_waitcnt vmcnt(6)" ::: "memory");
        __builtin_amdgcn_sched_barrier(0);

        const char* Kb = sKbf + kcur * 8192;
        const char* Vb = sVbf + (t & 1) * 8192;

        // ---- St = K·Q^T per 32-kv tile: 4 MFMA each ----
        f32x16 st[2];
        __builtin_amdgcn_s_setprio(1);
#pragma unroll
        for (int kt = 0; kt < 2; kt++) {
            int row = kt * 32 + l31;
            f32x16 s = 0.f;
#pragma unroll
            for (int c = 0; c < 4; c++) {
                f16x8 kf = *(const f16x8*)(Kb + (((row << 7) | (c << 5) | (hh << 4)) ^ swz));
                s = __builtin_amdgcn_mfma_f32_32x32x16_f16(kf, qf[c], s, 0, 0, 0);
            }
            st[kt] = s;
        }
        __builtin_amdgcn_s_setprio(0);

        // ---- P = exp2(St); l-sum (own half, f32 tree); pack quads ----
        u32x2 qw[2][4];
#pragma unroll
        for (int kt = 0; kt < 2; kt++) {
            float p[16];
#pragma unroll
            for (int i = 0; i < 16; i++) p[i] = __builtin_amdgcn_exp2f(st[kt][i]);
            l_run += ((p[0] + p[1]) + (p[2] + p[3])) + ((p[4] + p[5]) + (p[6] + p[7]))
                   + ((p[8] + p[9]) + (p[10] + p[11])) + ((p[12] + p[13]) + (p[14] + p[15]));
#pragma unroll
            for (int rq = 0; rq < 4; rq++) {
                f16x4 qd = {(f16)p[4 * rq], (f16)p[4 * rq + 1], (f16)p[4 * rq + 2], (f16)p[4 * rq + 3]};
                qw[kt][rq] = __builtin_bit_cast(u32x2, qd);
            }
        }

        // ---- repack to PV B-frags + PV MFMAs ----
#pragma unroll
        for (int kt = 0; kt < 2; kt++) {
#pragma unroll
            for (int c2 = 0; c2 < 2; c2++) {
                unsigned a0 = qw[kt][2 * c2][0],     a1 = qw[kt][2 * c2][1];      // Q_{2c}
                unsigned b0 = qw[kt][2 * c2 + 1][0], b1 = qw[kt][2 * c2 + 1][1];  // Q_{2c+1}
                unsigned ca0 = (unsigned)__shfl_xor((int)a0, 32);
                unsigned ca1 = (unsigned)__shfl_xor((int)a1, 32);
                unsigned cb0 = (unsigned)__shfl_xor((int)b0, 32);
                unsigned cb1 = (unsigned)__shfl_xor((int)b1, 32);
                u32x4 bw;
                bw[0] = hh ? cb0 : a0;    // Blo = [Q2c.lo | Q2c1.lo]
                bw[1] = hh ? cb1 : a1;
                bw[2] = hh ? b0 : ca0;    // Bhi = [Q2c.hi | Q2c1.hi]
                bw[3] = hh ? b1 : ca1;
                f16x8 bf = __builtin_bit_cast(f16x8, bw);
                const int cg = kt * 2 + c2;            // kv chunk 0..3
                __builtin_amdgcn_s_setprio(1);
                {
                    int row0 = l31;                    // d-tile 0
                    f16x8 vf0 = *(const f16x8*)(Vb + (((row0 << 7) | (cg << 5) | (hh << 4)) ^ swz));
                    Ot0 = __builtin_amdgcn_mfma_f32_32x32x16_f16(vf0, bf, Ot0, 0, 0, 0);
                    int row1 = 32 + l31;               // d-tile 1
                    f16x8 vf1 = *(const f16x8*)(Vb + (((row1 << 7) | (cg << 5) | (hh << 4)) ^ swz));
                    Ot1 = __builtin_amdgcn_mfma_f32_32x32x16_f16(vf1, bf, Ot1, 0, 0, 0);
                }
                __builtin_amdgcn_s_setprio(0);
            }
        }

        kcur = (kcur == 2) ? 0 : kcur + 1;
        kpre = (kpre == 2) ? 0 : kpre + 1;
    }

    // ---- epilogue: l = own + cross half; divide; write O^T as [n][d] ----
    l_run += __shfl_xor(l_run, 32);
    float inv = 1.0f / l_run;
#pragma unroll
    for (int dt = 0; dt < 2; dt++) {
        const f32x16& O = dt ? Ot1 : Ot0;
#pragma unroll
        for (int rq = 0; rq < 4; rq++) {
            f16x4 o;
#pragma unroll
            for (int r = 0; r < 4; r++) o[r] = (f16)(O[4 * rq + r] * inv);
            int d0 = dt * 32 + rq * 8 + hh * 4;
            *(f16x4*)&cat[((size_t)(b * N_ + qrow)) * 1024 + h_head * 128 + d0] = o;
        }
    }
}

// ---------------- Gaussian positional branch: normalized band conv ----------------
__global__ __launch_bounds__(256) void gauss_k(
    const float* __restrict__ vsb, const float* __restrict__ sigma, f16* __restrict__ cat)
{
    const int tid = threadIdx.x;
    const int bh = blockIdx.y, b = bh >> 3, h = bh & 7;
    const int i0 = blockIdx.x * 64;
    const int wv = tid >> 6, d = tid & 63;
    const float sig = sigma[h];
    const float c = 0.72134752f / (sig * sig);   // log2(e)/(2 sig^2)

    float wt[17];
#pragma unroll
    for (int o = 0; o <= 16; o++) wt[o] = __builtin_amdgcn_exp2f(-(float)(o * o) * c);
    float wfull = wt[0];
#pragma unroll
    for (int o = 1; o <= 16; o++) wfull += 2.f * wt[o];
    const float inv_wfull = 1.0f / wfull;

    const size_t base = (size_t)bh * N_ * DH_;
    const int r0 = i0 + wv * 16 - 16;
    float v[48];
#pragma unroll
    for (int k = 0; k < 48; k++) {
        int r = r0 + k; r = r < 0 ? 0 : (r > N_ - 1 ? N_ - 1 : r);
        v[k] = vsb[base + (size_t)r * DH_ + d];
    }

#pragma unroll
    for (int it = 0; it < 16; it++) {
        int i = i0 + wv * 16 + it;
        float acc = 0.f;
        if (i >= 16 && i <= N_ - 17) {
#pragma unroll
            for (int o = -16; o <= 16; o++)
                acc += wt[o < 0 ? -o : o] * v[16 + it + o];
            acc *= inv_wfull;
        } else {
            float ws = 0.f;
#pragma unroll
            for (int o = -16; o <= 16; o++) {
                int j = i + o;
                if (j >= 0 && j <= N_ - 1) {
                    float w = wt[o < 0 ? -o : o];
                    ws += w;
                    acc += w * v[16 + it + o];
                }
            }
            acc /= ws;
        }
        cat[((size_t)(b * N_ + i)) * 1024 + h * 128 + 64 + d] = (f16)acc;
    }
}

// ---------------- launch ----------------

extern "C" void kernel_launch(void* const* d_in, const int* in_sizes, int n_in,
                              void* d_out, int out_size, void* d_ws, size_t ws_size,
                              hipStream_t stream) {
    const float* x      = (const float*)d_in[0];
    const float* w_qkvg = (const float*)d_in[1];
    const float* sigma  = (const float*)d_in[2];
    const float* w_out  = (const float*)d_in[3];
    const float* b_out  = (const float*)d_in[4];
    float* out = (float*)d_out;
    char* ws = (char*)d_ws;

    const size_t MB = 1048576;
    f16*   x16 = (f16*)(ws);                 //  8 MB  [8192][512]
    f16*   wqT = (f16*)(ws + 8 * MB);        //  2 MB  [2048][512]
    f16*   woT = (f16*)(ws + 10 * MB);       //  1 MB  [512][1024]
    f16*   qb  = (f16*)(ws + 11 * MB);       //  8 MB  [32][2048][64]
    f16*   kb  = (f16*)(ws + 19 * MB);       //  8 MB
    f16*   vbT = (f16*)(ws + 27 * MB);       //  8 MB  [32][64][2048]
    float* vsb = (float*)(ws + 35 * MB);     // 16 MB  f32
    f16*   cat = (f16*)(ws + 51 * MB);       // 16 MB  [8192][1024]
    if (ws_size < 67 * MB) return;           // scratch guard

    cvt_f16_k8<<<2048, 256, 0, stream>>>(x, x16, B_ * N_ * DIM_ / 8);
    transpose_cvt_k<<<256, 256, 0, stream>>>(w_qkvg, wqT, 512, 2048);
    transpose_cvt_k<<<128, 256, 0, stream>>>(w_out, woT, 1024, 512);

    gemm_bt<0><<<dim3(16, 64), 256, 0, stream>>>(x16, wqT, 512, 2048,
                                                 qb, kb, vbT, vsb, nullptr, nullptr);

    attn_k<<<512, 256, 0, stream>>>(qb, kb, vbT, cat);
    gauss_k<<<dim3(32, 32), 256, 0, stream>>>(vsb, sigma, cat);

    gemm_small<<<dim3(8, 128), 256, 0, stream>>>(cat, woT, 1024, 512, b_out, out);
}

// Round 12
// 135.545 us; speedup vs baseline: 1.0074x; 1.0074x over previous
//
#include <hip/hip_runtime.h>

typedef _Float16 f16;
typedef __attribute__((ext_vector_type(8))) _Float16 f16x8;
typedef __attribute__((ext_vector_type(4))) _Float16 f16x4;
typedef __attribute__((ext_vector_type(4))) float f32x4;

#define B_ 4
#define N_ 2048
#define DIM_ 512
#define H_ 8
#define DH_ 64

// global -> LDS direct (16B per lane). LDS dest must be wave-uniform;
// global src is per-lane (pre-swizzled). Size must be literal 16.
__device__ __forceinline__ void gload16(const void* g, void* l) {
    __builtin_amdgcn_global_load_lds((const __attribute__((address_space(1))) void*)g,
                                     (__attribute__((address_space(3))) void*)l, 16, 0, 0);
}

// ---------------- small conversion kernels ----------------

__global__ __launch_bounds__(256) void cvt_f16_k8(const float* __restrict__ in,
                                                  f16* __restrict__ out, int n8) {
    int i = blockIdx.x * 256 + threadIdx.x;
    if (i < n8) {
        const float4 a = ((const float4*)in)[i * 2];
        const float4 b = ((const float4*)in)[i * 2 + 1];
        f16x8 o = {(f16)a.x, (f16)a.y, (f16)a.z, (f16)a.w,
                   (f16)b.x, (f16)b.y, (f16)b.z, (f16)b.w};
        ((f16x8*)out)[i] = o;
    }
}

// out[n*K + k] = (f16) in[k*N + n]; LDS-tiled 64x64, coalesced on both sides.
__global__ __launch_bounds__(256) void transpose_cvt_k(const float* __restrict__ in,
                                                       f16* __restrict__ out, int K, int N) {
    __shared__ f16 tile[64][72];            // [n][k], +8 pad
    const int nbk = K >> 6;
    const int bk = blockIdx.x % nbk, bn = blockIdx.x / nbk;
    const int k0 = bk << 6, n0 = bn << 6;
    const int t = threadIdx.x;
    const int r = t >> 2, q = (t & 3) << 4;
#pragma unroll
    for (int u = 0; u < 4; u++) {
        const float4 v = *(const float4*)&in[(size_t)(k0 + r) * N + n0 + q + u * 4];
        tile[q + u * 4 + 0][r] = (f16)v.x;
        tile[q + u * 4 + 1][r] = (f16)v.y;
        tile[q + u * 4 + 2][r] = (f16)v.z;
        tile[q + u * 4 + 3][r] = (f16)v.w;
    }
    __syncthreads();
#pragma unroll
    for (int u = 0; u < 2; u++) {
        f16x8 o = *(const f16x8*)&tile[r][q + u * 8];
        *(f16x8*)&out[(size_t)(n0 + r) * K + k0 + q + u * 8] = o;
    }
}

// ---------------- GEMM: C = A[M][K] * BT[N][K]^T (m97 structure) ----------------
template <int EPI>
__global__ __launch_bounds__(256) void gemm_bt(
    const f16* __restrict__ A, const f16* __restrict__ BT, int K, int N,
    f16* __restrict__ qb, f16* __restrict__ kb, f16* __restrict__ vbT,
    f16* __restrict__ vs16, const float* __restrict__ bias, float* __restrict__ outp)
{
    __shared__ char sAb[16384];   // [128 m][64 k] f16, swizzled
    __shared__ char sBb[16384];   // [128 n][64 k] f16, swizzled
    const int tid = threadIdx.x;
    const int m0 = blockIdx.y * 128, n0 = blockIdx.x * 128;
    const int wave = tid >> 6, lane = tid & 63;
    const int wr = wave >> 1, wc = wave & 1;
    const int lr = lane & 15, lg = lane >> 4;

    f32x4 acc[4][4];
    const f32x4 zero = {0.f, 0.f, 0.f, 0.f};
#pragma unroll
    for (int i = 0; i < 4; i++)
#pragma unroll
        for (int j = 0; j < 4; j++) acc[i][j] = zero;

    const f16* srcA[4]; const f16* srcB[4];
    char* ldsA[4]; char* ldsB[4];
#pragma unroll
    for (int u = 0; u < 4; u++) {
        int row = wave * 8 + u * 32 + (lane >> 3);
        int e0 = ((lane & 7) ^ (row & 7)) << 3;
        srcA[u] = A + (size_t)(m0 + row) * K + e0;
        srcB[u] = BT + (size_t)(n0 + row) * K + e0;
        ldsA[u] = sAb + wave * 1024 + u * 4096;
        ldsB[u] = sBb + wave * 1024 + u * 4096;
    }

    const int swz = (lr & 7) << 4;
    for (int kt = 0; kt < K; kt += 64) {
#pragma unroll
        for (int u = 0; u < 4; u++) {
            gload16(srcA[u], ldsA[u]);
            gload16(srcB[u], ldsB[u]);
            srcA[u] += 64; srcB[u] += 64;
        }
        __syncthreads();
#pragma unroll
        for (int half = 0; half < 2; half++) {
            f16x8 af[4], bf[4];
#pragma unroll
            for (int i = 0; i < 4; i++) {
                int R = wr * 64 + i * 16 + lr;
                af[i] = *(const f16x8*)(sAb + R * 128 + (((half << 6) | (lg << 4)) ^ swz));
            }
#pragma unroll
            for (int j = 0; j < 4; j++) {
                int R = wc * 64 + j * 16 + lr;
                bf[j] = *(const f16x8*)(sBb + R * 128 + (((half << 6) | (lg << 4)) ^ swz));
            }
#pragma unroll
            for (int i = 0; i < 4; i++)
#pragma unroll
                for (int j = 0; j < 4; j++)
                    acc[i][j] = __builtin_amdgcn_mfma_f32_16x16x32_f16(af[i], bf[j], acc[i][j], 0, 0, 0);
        }
        __syncthreads();
    }

#pragma unroll
    for (int i = 0; i < 4; i++) {
#pragma unroll
        for (int j = 0; j < 4; j++) {
            int col = n0 + wc * 64 + j * 16 + lr;
            int row0 = m0 + wr * 64 + i * 16 + lg * 4;
            if (EPI == 0) {
                int sec = col >> 9, cc = col & 511;
                int h = cc >> 6, d = cc & 63;
                int b = row0 >> 11, ns = row0 & 2047;
                if (sec == 2) {
                    f16x4 o;
#pragma unroll
                    for (int r = 0; r < 4; r++) o[r] = (f16)acc[i][j][r];
                    *(f16x4*)&vbT[((size_t)(b * H_ + h) * DH_ + d) * N_ + ns] = o;
                } else if (sec == 0) {
#pragma unroll
                    for (int r = 0; r < 4; r++)
                        qb[((size_t)(b * H_ + h) * N_ + ns + r) * DH_ + d] = (f16)(acc[i][j][r] * 0.1803368801f);
                } else if (sec == 1) {
#pragma unroll
                    for (int r = 0; r < 4; r++)
                        kb[((size_t)(b * H_ + h) * N_ + ns + r) * DH_ + d] = (f16)acc[i][j][r];
                } else {
#pragma unroll
                    for (int r = 0; r < 4; r++)
                        vs16[((size_t)(b * H_ + h) * N_ + ns + r) * DH_ + d] = (f16)acc[i][j][r];
                }
            } else {
#pragma unroll
                for (int r = 0; r < 4; r++)
                    outp[(size_t)(row0 + r) * N + col] = acc[i][j][r] + bias[col];
            }
        }
    }
}

// ---------------- small-N GEMM (final projection): 64x64 tile ----------------
__global__ __launch_bounds__(256) void gemm_small(
    const f16* __restrict__ A, const f16* __restrict__ BT, int K, int N,
    const float* __restrict__ bias, float* __restrict__ outp)
{
    __shared__ char sAb[8192];
    __shared__ char sBb[8192];
    const int tid = threadIdx.x;
    const int m0 = blockIdx.y * 64, n0 = blockIdx.x * 64;
    const int wave = tid >> 6, lane = tid & 63;
    const int wr = wave >> 1, wc = wave & 1;
    const int lr = lane & 15, lg = lane >> 4;

    f32x4 acc[2][2];
    const f32x4 zero = {0.f, 0.f, 0.f, 0.f};
#pragma unroll
    for (int i = 0; i < 2; i++)
#pragma unroll
        for (int j = 0; j < 2; j++) acc[i][j] = zero;

    const f16* srcA[2]; const f16* srcB[2];
    char* ldsA[2]; char* ldsB[2];
#pragma unroll
    for (int u = 0; u < 2; u++) {
        int row = wave * 8 + u * 32 + (lane >> 3);
        int e0 = ((lane & 7) ^ (row & 7)) << 3;
        srcA[u] = A + (size_t)(m0 + row) * K + e0;
        srcB[u] = BT + (size_t)(n0 + row) * K + e0;
        ldsA[u] = sAb + wave * 1024 + u * 4096;
        ldsB[u] = sBb + wave * 1024 + u * 4096;
    }

    const int swz = (lr & 7) << 4;
    for (int kt = 0; kt < K; kt += 64) {
#pragma unroll
        for (int u = 0; u < 2; u++) {
            gload16(srcA[u], ldsA[u]);
            gload16(srcB[u], ldsB[u]);
            srcA[u] += 64; srcB[u] += 64;
        }
        __syncthreads();
#pragma unroll
        for (int half = 0; half < 2; half++) {
            f16x8 af[2], bf[2];
#pragma unroll
            for (int i = 0; i < 2; i++) {
                int R = wr * 32 + i * 16 + lr;
                af[i] = *(const f16x8*)(sAb + R * 128 + (((half << 6) | (lg << 4)) ^ swz));
            }
#pragma unroll
            for (int j = 0; j < 2; j++) {
                int R = wc * 32 + j * 16 + lr;
                bf[j] = *(const f16x8*)(sBb + R * 128 + (((half << 6) | (lg << 4)) ^ swz));
            }
#pragma unroll
            for (int i = 0; i < 2; i++)
#pragma unroll
                for (int j = 0; j < 2; j++)
                    acc[i][j] = __builtin_amdgcn_mfma_f32_16x16x32_f16(af[i], bf[j], acc[i][j], 0, 0, 0);
        }
        __syncthreads();
    }

#pragma unroll
    for (int i = 0; i < 2; i++)
#pragma unroll
        for (int j = 0; j < 2; j++) {
            int col = n0 + wc * 32 + j * 16 + lr;
            int row0 = m0 + wr * 32 + i * 16 + lg * 4;
#pragma unroll
            for (int r = 0; r < 4; r++)
                outp[(size_t)(row0 + r) * N + col] = acc[i][j][r] + bias[col];
        }
}

// ---------------- flash attention (softmax branch), KV-split ----------------
// R10 post-mortem: 16-waves/CU configs are LDS-BW-bound (~62us); halving LDS
// traffic via 32q/wave (R9) halved the grid to 2 blocks/CU and went
// latency-bound at the same 63us. Fix: split KV in two — with static-max
// (m=0) softmax, partials from disjoint KV ranges combine by PURE ADDITION.
// Grid = 32bh x 16qblk(128q) x 2 kv-halves = 1024 blocks (4/CU, 16 waves/CU)
// of the R9 body (4 waves x 32q, halved LDS reads/output), 16 tiles each.
// Half 0 writes raw f16 O into cat; half 1 into oaccB; l's to lacc (f32).
// combine_k then does (O_A + O_B) / (l_A + l_B).
__global__ __launch_bounds__(256) void attn_k(
    const f16* __restrict__ qb, const f16* __restrict__ kb, const f16* __restrict__ vbT,
    f16* __restrict__ cat, f16* __restrict__ oaccB, float* __restrict__ lacc)
{
    __shared__ char sKbf[3 * 8192];   // K bufs, [64 kv][64 dh] f16, swizzled
    __shared__ char sVbf[2 * 8192];   // V bufs, [64 d ][64 kv] f16, swizzled
    const int tid = threadIdx.x;
    const int bid0 = blockIdx.x;
    const int obid = (bid0 & 7) * 128 + (bid0 >> 3);   // bijective XCD swizzle (1024 = 8*128)
    const int bh = obid >> 5, qblk = (obid >> 1) & 15, half = obid & 1;
    const int b = bh >> 3, h = bh & 7;
    const int hn = half << 4;                          // base kv tile of this half
    const int wave = tid >> 6, lane = tid & 63;
    const int lr = lane & 15, lg = lane >> 4;

    const size_t base = (size_t)bh * N_ * DH_;
    const int qrow_a = qblk * 128 + wave * 32 + lr;
    const int qrow_b = qrow_a + 16;
    const f16x8 qfa0 = *(const f16x8*)&qb[base + (size_t)qrow_a * DH_ + lg * 8];
    const f16x8 qfa1 = *(const f16x8*)&qb[base + (size_t)qrow_a * DH_ + 32 + lg * 8];
    const f16x8 qfb0 = *(const f16x8*)&qb[base + (size_t)qrow_b * DH_ + lg * 8];
    const f16x8 qfb1 = *(const f16x8*)&qb[base + (size_t)qrow_b * DH_ + 32 + lg * 8];

    // per-lane staging sources (pre-swizzled); kv tile T: K at +T*4096, V at +T*64
    const f16* kq[2]; const f16* vq[2];
#pragma unroll
    for (int u = 0; u < 2; u++) {
        int row = wave * 8 + u * 32 + (lane >> 3);
        int e0 = ((lane & 7) ^ (row & 7)) << 3;
        kq[u] = kb + base + (size_t)row * 64 + e0;
        vq[u] = vbT + base + (size_t)row * 2048 + e0;
    }
    char* const ldsKw = sKbf + wave * 1024;
    char* const ldsVw = sVbf + wave * 1024;

    f32x4 Ota[4], Otb[4], lacc_a, lacc_b;
    const f32x4 zero = {0.f, 0.f, 0.f, 0.f};
#pragma unroll
    for (int dt = 0; dt < 4; dt++) { Ota[dt] = zero; Otb[dt] = zero; }
    lacc_a = zero; lacc_b = zero;
    const f16x4 onesA = {(f16)1.f, (f16)1.f, (f16)1.f, (f16)1.f};

    const int swz = (lr & 7) << 4;

    // prologue: K(hn), V(hn), K(hn+1)
#pragma unroll
    for (int u = 0; u < 2; u++) gload16(kq[u] + (size_t)hn * 4096, ldsKw + u * 4096);
#pragma unroll
    for (int u = 0; u < 2; u++) gload16(vq[u] + hn * 64, ldsVw + u * 4096);
#pragma unroll
    for (int u = 0; u < 2; u++) gload16(kq[u] + (size_t)(hn + 1) * 4096, ldsKw + 8192 + u * 4096);

    int kcur = 0, kpre = 2;
    for (int t = 0; t < 16; t++) {
        __builtin_amdgcn_s_barrier();
        {   // issue V(t+1), K(t+2), wrapped mod 16 within this half
            const int vtn = hn + ((t + 1) & 15), ktn = hn + ((t + 2) & 15);
            char* vdst = ldsVw + ((t + 1) & 1) * 8192;
            char* kdst = ldsKw + kpre * 8192;
#pragma unroll
            for (int u = 0; u < 2; u++) gload16(vq[u] + vtn * 64, vdst + u * 4096);
#pragma unroll
            for (int u = 0; u < 2; u++) gload16(kq[u] + (size_t)ktn * 4096, kdst + u * 4096);
        }
        asm volatile("s_waitcnt vmcnt(6)" ::: "memory");   // K(t),V(t) landed; 6 in flight
        __builtin_amdgcn_sched_barrier(0);

        const char* Kb = sKbf + kcur * 8192;
        const char* Vb = sVbf + (t & 1) * 8192;

        // ---- St = K·Q^T for both q-halves; K-frags read once ----
        f32x4 sta[4], stb[4];
        __builtin_amdgcn_s_setprio(1);
#pragma unroll
        for (int ct = 0; ct < 4; ct++) {
            int row = ct * 16 + lr;
            f16x8 kf0 = *(const f16x8*)(Kb + (((row << 7) | (lg << 4)) ^ swz));
            f16x8 kf1 = *(const f16x8*)(Kb + (((row << 7) | 64 | (lg << 4)) ^ swz));
            f32x4 sa = __builtin_amdgcn_mfma_f32_16x16x32_f16(kf0, qfa0, zero, 0, 0, 0);
            sta[ct]  = __builtin_amdgcn_mfma_f32_16x16x32_f16(kf1, qfa1, sa, 0, 0, 0);
            f32x4 sb = __builtin_amdgcn_mfma_f32_16x16x32_f16(kf0, qfb0, zero, 0, 0, 0);
            stb[ct]  = __builtin_amdgcn_mfma_f32_16x16x32_f16(kf1, qfb1, sb, 0, 0, 0);
        }
        __builtin_amdgcn_s_setprio(0);

        // ---- P = exp2(St) (static max), packed to f16 B-frags ----
        f16x4 ppa[4], ppb[4];
#pragma unroll
        for (int ct = 0; ct < 4; ct++)
#pragma unroll
            for (int r = 0; r < 4; r++) {
                ppa[ct][r] = (f16)__builtin_amdgcn_exp2f(sta[ct][r]);
                ppb[ct][r] = (f16)__builtin_amdgcn_exp2f(stb[ct][r]);
            }

        // ---- PV + l-sum on the MFMA pipe; V-frags read once ----
        __builtin_amdgcn_s_setprio(1);
#pragma unroll
        for (int ct = 0; ct < 4; ct++) {
            lacc_a = __builtin_amdgcn_mfma_f32_16x16x16f16(onesA, ppa[ct], lacc_a, 0, 0, 0);
            lacc_b = __builtin_amdgcn_mfma_f32_16x16x16f16(onesA, ppb[ct], lacc_b, 0, 0, 0);
        }
#pragma unroll
        for (int dt = 0; dt < 4; dt++) {
            int row = dt * 16 + lr;
#pragma unroll
            for (int ct = 0; ct < 4; ct++) {
                f16x4 vt = *(const f16x4*)(Vb + (((row << 7) | (ct * 32) | (lg << 3)) ^ swz));
                Ota[dt] = __builtin_amdgcn_mfma_f32_16x16x16f16(vt, ppa[ct], Ota[dt], 0, 0, 0);
                Otb[dt] = __builtin_amdgcn_mfma_f32_16x16x16f16(vt, ppb[ct], Otb[dt], 0, 0, 0);
            }
        }
        __builtin_amdgcn_s_setprio(0);

        kcur = (kcur == 2) ? 0 : kcur + 1;
        kpre = (kpre == 2) ? 0 : kpre + 1;
    }

    // ---- epilogue: write RAW partial O (f16) + l (f32); combine_k finishes ----
#pragma unroll
    for (int dt = 0; dt < 4; dt++) {
        f16x4 oa, ob;
#pragma unroll
        for (int r = 0; r < 4; r++) {
            oa[r] = (f16)Ota[dt][r];
            ob[r] = (f16)Otb[dt][r];
        }
        if (half == 0) {
            *(f16x4*)&cat[((size_t)(b * N_ + qrow_a)) * 1024 + h * 128 + dt * 16 + lg * 4] = oa;
            *(f16x4*)&cat[((size_t)(b * N_ + qrow_b)) * 1024 + h * 128 + dt * 16 + lg * 4] = ob;
        } else {
            *(f16x4*)&oaccB[((size_t)(bh * N_ + qrow_a)) * 64 + dt * 16 + lg * 4] = oa;
            *(f16x4*)&oaccB[((size_t)(bh * N_ + qrow_b)) * 64 + dt * 16 + lg * 4] = ob;
        }
    }
    if (lg == 0) {   // every lane's lacc[0] = full row-sum for q = lr (ones-trick)
        lacc[half * (32 * N_) + bh * N_ + qrow_a] = lacc_a[0];
        lacc[half * (32 * N_) + bh * N_ + qrow_b] = lacc_b[0];
    }
}

// ---------------- combine: cat = (O_A + O_B) / (l_A + l_B) ----------------
__global__ __launch_bounds__(256) void combine_k(
    f16* __restrict__ cat, const f16* __restrict__ oaccB, const float* __restrict__ lacc)
{
    int gi = blockIdx.x * 256 + threadIdx.x;      // 524288 = 65536 rows x 8
    int row = gi >> 3, c8 = gi & 7;               // row over [bh][q]
    int bh = row >> 11, q = row & 2047;
    int b = bh >> 3, h = bh & 7;
    float inv = 1.0f / (lacc[row] + lacc[32 * N_ + row]);
    f16* cp = &cat[((size_t)(b * N_ + q)) * 1024 + h * 128 + c8 * 8];
    f16x8 a = *(const f16x8*)cp;
    f16x8 o2 = *(const f16x8*)&oaccB[(size_t)row * 64 + c8 * 8];
    f16x8 o;
#pragma unroll
    for (int i = 0; i < 8; i++) o[i] = (f16)(((float)a[i] + (float)o2[i]) * inv);
    *(f16x8*)cp = o;
}

// ---------------- Gaussian positional branch: normalized band conv ----------------
__global__ __launch_bounds__(256) void gauss_k(
    const f16* __restrict__ vs16, const float* __restrict__ sigma, f16* __restrict__ cat)
{
    const int tid = threadIdx.x;
    const int bh = blockIdx.y, b = bh >> 3, h = bh & 7;
    const int i0 = blockIdx.x * 64;
    const int wv = tid >> 6, d = tid & 63;
    const float sig = sigma[h];
    const float c = 0.72134752f / (sig * sig);   // log2(e)/(2 sig^2)

    float wt[17];
#pragma unroll
    for (int o = 0; o <= 16; o++) wt[o] = __builtin_amdgcn_exp2f(-(float)(o * o) * c);
    float wfull = wt[0];
#pragma unroll
    for (int o = 1; o <= 16; o++) wfull += 2.f * wt[o];
    const float inv_wfull = 1.0f / wfull;

    const size_t base = (size_t)bh * N_ * DH_;
    const int r0 = i0 + wv * 16 - 16;
    float v[48];
#pragma unroll
    for (int k = 0; k < 48; k++) {
        int r = r0 + k; r = r < 0 ? 0 : (r > N_ - 1 ? N_ - 1 : r);
        v[k] = (float)vs16[base + (size_t)r * DH_ + d];
    }

#pragma unroll
    for (int it = 0; it < 16; it++) {
        int i = i0 + wv * 16 + it;
        float acc = 0.f;
        if (i >= 16 && i <= N_ - 17) {
#pragma unroll
            for (int o = -16; o <= 16; o++)
                acc += wt[o < 0 ? -o : o] * v[16 + it + o];
            acc *= inv_wfull;
        } else {
            float ws = 0.f;
#pragma unroll
            for (int o = -16; o <= 16; o++) {
                int j = i + o;
                if (j >= 0 && j <= N_ - 1) {
                    float w = wt[o < 0 ? -o : o];
                    ws += w;
                    acc += w * v[16 + it + o];
                }
            }
            acc /= ws;
        }
        cat[((size_t)(b * N_ + i)) * 1024 + h * 128 + 64 + d] = (f16)acc;
    }
}

// ---------------- launch ----------------

extern "C" void kernel_launch(void* const* d_in, const int* in_sizes, int n_in,
                              void* d_out, int out_size, void* d_ws, size_t ws_size,
                              hipStream_t stream) {
    const float* x      = (const float*)d_in[0];
    const float* w_qkvg = (const float*)d_in[1];
    const float* sigma  = (const float*)d_in[2];
    const float* w_out  = (const float*)d_in[3];
    const float* b_out  = (const float*)d_in[4];
    float* out = (float*)d_out;
    char* ws = (char*)d_ws;

    const size_t MB = 1048576;
    f16*   x16  = (f16*)(ws);                // 0-8 MB   (dead after gemm0)
    float* lacc = (float*)(ws);              // 0-0.5 MB (overlays dead x16; attn+)
    f16*   wqT  = (f16*)(ws + 8 * MB);       // 8-10
    f16*   woT  = (f16*)(ws + 10 * MB);      // 10-11
    f16*   qb   = (f16*)(ws + 11 * MB);      // 11-19
    f16*   kb   = (f16*)(ws + 19 * MB);      // 19-27
    f16*   vbT  = (f16*)(ws + 27 * MB);      // 27-35  [bh][dh][n]
    f16*   vs16 = (f16*)(ws + 35 * MB);      // 35-43  vsigma f16
    f16*   cat  = (f16*)(ws + 43 * MB);      // 43-59  [8192][1024]
    f16*   oaccB= (f16*)(ws + 59 * MB);      // 59-67  [32][2048][64]
    if (ws_size < 67 * MB) return;           // scratch guard

    cvt_f16_k8<<<2048, 256, 0, stream>>>(x, x16, B_ * N_ * DIM_ / 8);
    transpose_cvt_k<<<256, 256, 0, stream>>>(w_qkvg, wqT, 512, 2048);
    transpose_cvt_k<<<128, 256, 0, stream>>>(w_out, woT, 1024, 512);

    gemm_bt<0><<<dim3(16, 64), 256, 0, stream>>>(x16, wqT, 512, 2048,
                                                 qb, kb, vbT, vs16, nullptr, nullptr);

    attn_k<<<1024, 256, 0, stream>>>(qb, kb, vbT, cat, oaccB, lacc);
    combine_k<<<2048, 256, 0, stream>>>(cat, oaccB, lacc);
    gauss_k<<<dim3(32, 32), 256, 0, stream>>>(vs16, sigma, cat);

    gemm_small<<<dim3(8, 128), 256, 0, stream>>>(cat, woT, 1024, 512, b_out, out);
}

// Round 13
// 130.912 us; speedup vs baseline: 1.0430x; 1.0354x over previous
//
#include <hip/hip_runtime.h>

typedef _Float16 f16;
typedef __attribute__((ext_vector_type(8))) _Float16 f16x8;
typedef __attribute__((ext_vector_type(4))) _Float16 f16x4;
typedef __attribute__((ext_vector_type(4))) float f32x4;

#define B_ 4
#define N_ 2048
#define DIM_ 512
#define H_ 8
#define DH_ 64

// global -> LDS direct (16B per lane). LDS dest must be wave-uniform;
// global src is per-lane (pre-swizzled). Size must be literal 16.
__device__ __forceinline__ void gload16(const void* g, void* l) {
    __builtin_amdgcn_global_load_lds((const __attribute__((address_space(1))) void*)g,
                                     (__attribute__((address_space(3))) void*)l, 16, 0, 0);
}

// ---------------- small conversion kernels ----------------

__global__ __launch_bounds__(256) void cvt_f16_k8(const float* __restrict__ in,
                                                  f16* __restrict__ out, int n8) {
    int i = blockIdx.x * 256 + threadIdx.x;
    if (i < n8) {
        const float4 a = ((const float4*)in)[i * 2];
        const float4 b = ((const float4*)in)[i * 2 + 1];
        f16x8 o = {(f16)a.x, (f16)a.y, (f16)a.z, (f16)a.w,
                   (f16)b.x, (f16)b.y, (f16)b.z, (f16)b.w};
        ((f16x8*)out)[i] = o;
    }
}

// out[n*K + k] = (f16) in[k*N + n]; LDS-tiled 64x64, coalesced on both sides.
__global__ __launch_bounds__(256) void transpose_cvt_k(const float* __restrict__ in,
                                                       f16* __restrict__ out, int K, int N) {
    __shared__ f16 tile[64][72];            // [n][k], +8 pad
    const int nbk = K >> 6;
    const int bk = blockIdx.x % nbk, bn = blockIdx.x / nbk;
    const int k0 = bk << 6, n0 = bn << 6;
    const int t = threadIdx.x;
    const int r = t >> 2, q = (t & 3) << 4;
#pragma unroll
    for (int u = 0; u < 4; u++) {
        const float4 v = *(const float4*)&in[(size_t)(k0 + r) * N + n0 + q + u * 4];
        tile[q + u * 4 + 0][r] = (f16)v.x;
        tile[q + u * 4 + 1][r] = (f16)v.y;
        tile[q + u * 4 + 2][r] = (f16)v.z;
        tile[q + u * 4 + 3][r] = (f16)v.w;
    }
    __syncthreads();
#pragma unroll
    for (int u = 0; u < 2; u++) {
        f16x8 o = *(const f16x8*)&tile[r][q + u * 8];
        *(f16x8*)&out[(size_t)(n0 + r) * K + k0 + q + u * 8] = o;
    }
}

// ---------------- GEMM: C = A[M][K] * BT[N][K]^T (m97 structure) ----------------
template <int EPI>
__global__ __launch_bounds__(256) void gemm_bt(
    const f16* __restrict__ A, const f16* __restrict__ BT, int K, int N,
    f16* __restrict__ qb, f16* __restrict__ kb, f16* __restrict__ vbT,
    f16* __restrict__ vs16, const float* __restrict__ bias, float* __restrict__ outp)
{
    __shared__ char sAb[16384];   // [128 m][64 k] f16, swizzled
    __shared__ char sBb[16384];   // [128 n][64 k] f16, swizzled
    const int tid = threadIdx.x;
    const int m0 = blockIdx.y * 128, n0 = blockIdx.x * 128;
    const int wave = tid >> 6, lane = tid & 63;
    const int wr = wave >> 1, wc = wave & 1;
    const int lr = lane & 15, lg = lane >> 4;

    f32x4 acc[4][4];
    const f32x4 zero = {0.f, 0.f, 0.f, 0.f};
#pragma unroll
    for (int i = 0; i < 4; i++)
#pragma unroll
        for (int j = 0; j < 4; j++) acc[i][j] = zero;

    const f16* srcA[4]; const f16* srcB[4];
    char* ldsA[4]; char* ldsB[4];
#pragma unroll
    for (int u = 0; u < 4; u++) {
        int row = wave * 8 + u * 32 + (lane >> 3);
        int e0 = ((lane & 7) ^ (row & 7)) << 3;
        srcA[u] = A + (size_t)(m0 + row) * K + e0;
        srcB[u] = BT + (size_t)(n0 + row) * K + e0;
        ldsA[u] = sAb + wave * 1024 + u * 4096;
        ldsB[u] = sBb + wave * 1024 + u * 4096;
    }

    const int swz = (lr & 7) << 4;
    for (int kt = 0; kt < K; kt += 64) {
#pragma unroll
        for (int u = 0; u < 4; u++) {
            gload16(srcA[u], ldsA[u]);
            gload16(srcB[u], ldsB[u]);
            srcA[u] += 64; srcB[u] += 64;
        }
        __syncthreads();
#pragma unroll
        for (int half = 0; half < 2; half++) {
            f16x8 af[4], bf[4];
#pragma unroll
            for (int i = 0; i < 4; i++) {
                int R = wr * 64 + i * 16 + lr;
                af[i] = *(const f16x8*)(sAb + R * 128 + (((half << 6) | (lg << 4)) ^ swz));
            }
#pragma unroll
            for (int j = 0; j < 4; j++) {
                int R = wc * 64 + j * 16 + lr;
                bf[j] = *(const f16x8*)(sBb + R * 128 + (((half << 6) | (lg << 4)) ^ swz));
            }
#pragma unroll
            for (int i = 0; i < 4; i++)
#pragma unroll
                for (int j = 0; j < 4; j++)
                    acc[i][j] = __builtin_amdgcn_mfma_f32_16x16x32_f16(af[i], bf[j], acc[i][j], 0, 0, 0);
        }
        __syncthreads();
    }

#pragma unroll
    for (int i = 0; i < 4; i++) {
#pragma unroll
        for (int j = 0; j < 4; j++) {
            int col = n0 + wc * 64 + j * 16 + lr;
            int row0 = m0 + wr * 64 + i * 16 + lg * 4;
            if (EPI == 0) {
                int sec = col >> 9, cc = col & 511;
                int h = cc >> 6, d = cc & 63;
                int b = row0 >> 11, ns = row0 & 2047;
                if (sec == 2) {
                    f16x4 o;
#pragma unroll
                    for (int r = 0; r < 4; r++) o[r] = (f16)acc[i][j][r];
                    *(f16x4*)&vbT[((size_t)(b * H_ + h) * DH_ + d) * N_ + ns] = o;
                } else if (sec == 0) {
#pragma unroll
                    for (int r = 0; r < 4; r++)
                        qb[((size_t)(b * H_ + h) * N_ + ns + r) * DH_ + d] = (f16)(acc[i][j][r] * 0.1803368801f);
                } else if (sec == 1) {
#pragma unroll
                    for (int r = 0; r < 4; r++)
                        kb[((size_t)(b * H_ + h) * N_ + ns + r) * DH_ + d] = (f16)acc[i][j][r];
                } else {
#pragma unroll
                    for (int r = 0; r < 4; r++)
                        vs16[((size_t)(b * H_ + h) * N_ + ns + r) * DH_ + d] = (f16)acc[i][j][r];
                }
            } else {
#pragma unroll
                for (int r = 0; r < 4; r++)
                    outp[(size_t)(row0 + r) * N + col] = acc[i][j][r] + bias[col];
            }
        }
    }
}

// ---------------- small-N GEMM (final projection): 64x64 tile ----------------
__global__ __launch_bounds__(256) void gemm_small(
    const f16* __restrict__ A, const f16* __restrict__ BT, int K, int N,
    const float* __restrict__ bias, float* __restrict__ outp)
{
    __shared__ char sAb[8192];
    __shared__ char sBb[8192];
    const int tid = threadIdx.x;
    const int m0 = blockIdx.y * 64, n0 = blockIdx.x * 64;
    const int wave = tid >> 6, lane = tid & 63;
    const int wr = wave >> 1, wc = wave & 1;
    const int lr = lane & 15, lg = lane >> 4;

    f32x4 acc[2][2];
    const f32x4 zero = {0.f, 0.f, 0.f, 0.f};
#pragma unroll
    for (int i = 0; i < 2; i++)
#pragma unroll
        for (int j = 0; j < 2; j++) acc[i][j] = zero;

    const f16* srcA[2]; const f16* srcB[2];
    char* ldsA[2]; char* ldsB[2];
#pragma unroll
    for (int u = 0; u < 2; u++) {
        int row = wave * 8 + u * 32 + (lane >> 3);
        int e0 = ((lane & 7) ^ (row & 7)) << 3;
        srcA[u] = A + (size_t)(m0 + row) * K + e0;
        srcB[u] = BT + (size_t)(n0 + row) * K + e0;
        ldsA[u] = sAb + wave * 1024 + u * 4096;
        ldsB[u] = sBb + wave * 1024 + u * 4096;
    }

    const int swz = (lr & 7) << 4;
    for (int kt = 0; kt < K; kt += 64) {
#pragma unroll
        for (int u = 0; u < 2; u++) {
            gload16(srcA[u], ldsA[u]);
            gload16(srcB[u], ldsB[u]);
            srcA[u] += 64; srcB[u] += 64;
        }
        __syncthreads();
#pragma unroll
        for (int half = 0; half < 2; half++) {
            f16x8 af[2], bf[2];
#pragma unroll
            for (int i = 0; i < 2; i++) {
                int R = wr * 32 + i * 16 + lr;
                af[i] = *(const f16x8*)(sAb + R * 128 + (((half << 6) | (lg << 4)) ^ swz));
            }
#pragma unroll
            for (int j = 0; j < 2; j++) {
                int R = wc * 32 + j * 16 + lr;
                bf[j] = *(const f16x8*)(sBb + R * 128 + (((half << 6) | (lg << 4)) ^ swz));
            }
#pragma unroll
            for (int i = 0; i < 2; i++)
#pragma unroll
                for (int j = 0; j < 2; j++)
                    acc[i][j] = __builtin_amdgcn_mfma_f32_16x16x32_f16(af[i], bf[j], acc[i][j], 0, 0, 0);
        }
        __syncthreads();
    }

#pragma unroll
    for (int i = 0; i < 2; i++)
#pragma unroll
        for (int j = 0; j < 2; j++) {
            int col = n0 + wc * 32 + j * 16 + lr;
            int row0 = m0 + wr * 32 + i * 16 + lg * 4;
#pragma unroll
            for (int r = 0; r < 4; r++)
                outp[(size_t)(row0 + r) * N + col] = acc[i][j][r] + bias[col];
        }
}

// ---------------- flash attention (softmax branch), KV-split ----------------
// Structure = R11 (KV-split halves, pure-add combine, 4 waves x 32q, counted
// vmcnt). NEW (R12): PV and l-sum moved from K=16 MFMAs (half FLOP-rate) to
// 16x16x32 via the kv-permutation trick: softmax+PV sum over kv, so the K=32
// contraction slot (lg,j) is DEFINED to carry kv = 32c+16(j>>2)+4lg+(j&3).
// Then B-frag = concat(pp[2c], pp[2c+1]) — zero cross-lane ops — and the
// V A-frag is two b64 LDS reads (lo kv=32c+4lg, hi kv=32c+16+4lg), same
// read count as before. 56 MFMA (40 half-rate) -> 36 all full-rate.
__global__ __launch_bounds__(256) void attn_k(
    const f16* __restrict__ qb, const f16* __restrict__ kb, const f16* __restrict__ vbT,
    f16* __restrict__ cat, f16* __restrict__ oaccB, float* __restrict__ lacc)
{
    __shared__ char sKbf[3 * 8192];   // K bufs, [64 kv][64 dh] f16, swizzled
    __shared__ char sVbf[2 * 8192];   // V bufs, [64 d ][64 kv] f16, swizzled
    const int tid = threadIdx.x;
    const int bid0 = blockIdx.x;
    const int obid = (bid0 & 7) * 128 + (bid0 >> 3);   // bijective XCD swizzle (1024 = 8*128)
    const int bh = obid >> 5, qblk = (obid >> 1) & 15, half = obid & 1;
    const int b = bh >> 3, h = bh & 7;
    const int hn = half << 4;                          // base kv tile of this half
    const int wave = tid >> 6, lane = tid & 63;
    const int lr = lane & 15, lg = lane >> 4;

    const size_t base = (size_t)bh * N_ * DH_;
    const int qrow_a = qblk * 128 + wave * 32 + lr;
    const int qrow_b = qrow_a + 16;
    const f16x8 qfa0 = *(const f16x8*)&qb[base + (size_t)qrow_a * DH_ + lg * 8];
    const f16x8 qfa1 = *(const f16x8*)&qb[base + (size_t)qrow_a * DH_ + 32 + lg * 8];
    const f16x8 qfb0 = *(const f16x8*)&qb[base + (size_t)qrow_b * DH_ + lg * 8];
    const f16x8 qfb1 = *(const f16x8*)&qb[base + (size_t)qrow_b * DH_ + 32 + lg * 8];

    // per-lane staging sources (pre-swizzled); kv tile T: K at +T*4096, V at +T*64
    const f16* kq[2]; const f16* vq[2];
#pragma unroll
    for (int u = 0; u < 2; u++) {
        int row = wave * 8 + u * 32 + (lane >> 3);
        int e0 = ((lane & 7) ^ (row & 7)) << 3;
        kq[u] = kb + base + (size_t)row * 64 + e0;
        vq[u] = vbT + base + (size_t)row * 2048 + e0;
    }
    char* const ldsKw = sKbf + wave * 1024;
    char* const ldsVw = sVbf + wave * 1024;

    f32x4 Ota[4], Otb[4], lacc_a, lacc_b;
    const f32x4 zero = {0.f, 0.f, 0.f, 0.f};
#pragma unroll
    for (int dt = 0; dt < 4; dt++) { Ota[dt] = zero; Otb[dt] = zero; }
    lacc_a = zero; lacc_b = zero;
    const f16x8 ones8 = {(f16)1.f, (f16)1.f, (f16)1.f, (f16)1.f,
                         (f16)1.f, (f16)1.f, (f16)1.f, (f16)1.f};

    const int swz = (lr & 7) << 4;

    // prologue: K(hn), V(hn), K(hn+1)
#pragma unroll
    for (int u = 0; u < 2; u++) gload16(kq[u] + (size_t)hn * 4096, ldsKw + u * 4096);
#pragma unroll
    for (int u = 0; u < 2; u++) gload16(vq[u] + hn * 64, ldsVw + u * 4096);
#pragma unroll
    for (int u = 0; u < 2; u++) gload16(kq[u] + (size_t)(hn + 1) * 4096, ldsKw + 8192 + u * 4096);

    int kcur = 0, kpre = 2;
    for (int t = 0; t < 16; t++) {
        __builtin_amdgcn_s_barrier();
        {   // issue V(t+1), K(t+2), wrapped mod 16 within this half
            const int vtn = hn + ((t + 1) & 15), ktn = hn + ((t + 2) & 15);
            char* vdst = ldsVw + ((t + 1) & 1) * 8192;
            char* kdst = ldsKw + kpre * 8192;
#pragma unroll
            for (int u = 0; u < 2; u++) gload16(vq[u] + vtn * 64, vdst + u * 4096);
#pragma unroll
            for (int u = 0; u < 2; u++) gload16(kq[u] + (size_t)ktn * 4096, kdst + u * 4096);
        }
        asm volatile("s_waitcnt vmcnt(6)" ::: "memory");   // K(t),V(t) landed; 6 in flight
        __builtin_amdgcn_sched_barrier(0);

        const char* Kb = sKbf + kcur * 8192;
        const char* Vb = sVbf + (t & 1) * 8192;

        // ---- St = K·Q^T for both q-halves; K-frags read once ----
        f32x4 sta[4], stb[4];
        __builtin_amdgcn_s_setprio(1);
#pragma unroll
        for (int ct = 0; ct < 4; ct++) {
            int row = ct * 16 + lr;
            f16x8 kf0 = *(const f16x8*)(Kb + (((row << 7) | (lg << 4)) ^ swz));
            f16x8 kf1 = *(const f16x8*)(Kb + (((row << 7) | 64 | (lg << 4)) ^ swz));
            f32x4 sa = __builtin_amdgcn_mfma_f32_16x16x32_f16(kf0, qfa0, zero, 0, 0, 0);
            sta[ct]  = __builtin_amdgcn_mfma_f32_16x16x32_f16(kf1, qfa1, sa, 0, 0, 0);
            f32x4 sb = __builtin_amdgcn_mfma_f32_16x16x32_f16(kf0, qfb0, zero, 0, 0, 0);
            stb[ct]  = __builtin_amdgcn_mfma_f32_16x16x32_f16(kf1, qfb1, sb, 0, 0, 0);
        }
        __builtin_amdgcn_s_setprio(0);

        // ---- P = exp2(St) (static max), packed to f16 quads ----
        f16x4 ppa[4], ppb[4];
#pragma unroll
        for (int ct = 0; ct < 4; ct++)
#pragma unroll
            for (int r = 0; r < 4; r++) {
                ppa[ct][r] = (f16)__builtin_amdgcn_exp2f(sta[ct][r]);
                ppb[ct][r] = (f16)__builtin_amdgcn_exp2f(stb[ct][r]);
            }

        // ---- PV + l-sum on K=32 MFMAs (kv-permuted contraction) ----
        __builtin_amdgcn_s_setprio(1);
#pragma unroll
        for (int c = 0; c < 2; c++) {
            f16x8 bfa = __builtin_shufflevector(ppa[2 * c], ppa[2 * c + 1], 0, 1, 2, 3, 4, 5, 6, 7);
            f16x8 bfb = __builtin_shufflevector(ppb[2 * c], ppb[2 * c + 1], 0, 1, 2, 3, 4, 5, 6, 7);
            lacc_a = __builtin_amdgcn_mfma_f32_16x16x32_f16(ones8, bfa, lacc_a, 0, 0, 0);
            lacc_b = __builtin_amdgcn_mfma_f32_16x16x32_f16(ones8, bfb, lacc_b, 0, 0, 0);
#pragma unroll
            for (int dt = 0; dt < 4; dt++) {
                int row = dt * 16 + lr;
                // A-frag slot (lg,j): lo j=0..3 -> kv 32c+4lg+r, hi j=4..7 -> kv 32c+16+4lg+r
                f16x4 vlo = *(const f16x4*)(Vb + (((row << 7) | (c << 6) | (lg << 3)) ^ swz));
                f16x4 vhi = *(const f16x4*)(Vb + (((row << 7) | (c << 6) | 32 | (lg << 3)) ^ swz));
                f16x8 vf = __builtin_shufflevector(vlo, vhi, 0, 1, 2, 3, 4, 5, 6, 7);
                Ota[dt] = __builtin_amdgcn_mfma_f32_16x16x32_f16(vf, bfa, Ota[dt], 0, 0, 0);
                Otb[dt] = __builtin_amdgcn_mfma_f32_16x16x32_f16(vf, bfb, Otb[dt], 0, 0, 0);
            }
        }
        __builtin_amdgcn_s_setprio(0);

        kcur = (kcur == 2) ? 0 : kcur + 1;
        kpre = (kpre == 2) ? 0 : kpre + 1;
    }

    // ---- epilogue: write RAW partial O (f16) + l (f32); combine_k finishes ----
#pragma unroll
    for (int dt = 0; dt < 4; dt++) {
        f16x4 oa, ob;
#pragma unroll
        for (int r = 0; r < 4; r++) {
            oa[r] = (f16)Ota[dt][r];
            ob[r] = (f16)Otb[dt][r];
        }
        if (half == 0) {
            *(f16x4*)&cat[((size_t)(b * N_ + qrow_a)) * 1024 + h * 128 + dt * 16 + lg * 4] = oa;
            *(f16x4*)&cat[((size_t)(b * N_ + qrow_b)) * 1024 + h * 128 + dt * 16 + lg * 4] = ob;
        } else {
            *(f16x4*)&oaccB[((size_t)(bh * N_ + qrow_a)) * 64 + dt * 16 + lg * 4] = oa;
            *(f16x4*)&oaccB[((size_t)(bh * N_ + qrow_b)) * 64 + dt * 16 + lg * 4] = ob;
        }
    }
    if (lg == 0) {   // every lane's lacc[0] = full row-sum for q = lr (ones-trick)
        lacc[half * (32 * N_) + bh * N_ + qrow_a] = lacc_a[0];
        lacc[half * (32 * N_) + bh * N_ + qrow_b] = lacc_b[0];
    }
}

// ---------------- combine: cat = (O_A + O_B) / (l_A + l_B) ----------------
__global__ __launch_bounds__(256) void combine_k(
    f16* __restrict__ cat, const f16* __restrict__ oaccB, const float* __restrict__ lacc)
{
    int gi = blockIdx.x * 256 + threadIdx.x;      // 524288 = 65536 rows x 8
    int row = gi >> 3, c8 = gi & 7;               // row over [bh][q]
    int bh = row >> 11, q = row & 2047;
    int b = bh >> 3, h = bh & 7;
    float inv = 1.0f / (lacc[row] + lacc[32 * N_ + row]);
    f16* cp = &cat[((size_t)(b * N_ + q)) * 1024 + h * 128 + c8 * 8];
    f16x8 a = *(const f16x8*)cp;
    f16x8 o2 = *(const f16x8*)&oaccB[(size_t)row * 64 + c8 * 8];
    f16x8 o;
#pragma unroll
    for (int i = 0; i < 8; i++) o[i] = (f16)(((float)a[i] + (float)o2[i]) * inv);
    *(f16x8*)cp = o;
}

// ---------------- Gaussian positional branch: normalized band conv ----------------
__global__ __launch_bounds__(256) void gauss_k(
    const f16* __restrict__ vs16, const float* __restrict__ sigma, f16* __restrict__ cat)
{
    const int tid = threadIdx.x;
    const int bh = blockIdx.y, b = bh >> 3, h = bh & 7;
    const int i0 = blockIdx.x * 64;
    const int wv = tid >> 6, d = tid & 63;
    const float sig = sigma[h];
    const float c = 0.72134752f / (sig * sig);   // log2(e)/(2 sig^2)

    float wt[17];
#pragma unroll
    for (int o = 0; o <= 16; o++) wt[o] = __builtin_amdgcn_exp2f(-(float)(o * o) * c);
    float wfull = wt[0];
#pragma unroll
    for (int o = 1; o <= 16; o++) wfull += 2.f * wt[o];
    const float inv_wfull = 1.0f / wfull;

    const size_t base = (size_t)bh * N_ * DH_;
    const int r0 = i0 + wv * 16 - 16;
    float v[48];
#pragma unroll
    for (int k = 0; k < 48; k++) {
        int r = r0 + k; r = r < 0 ? 0 : (r > N_ - 1 ? N_ - 1 : r);
        v[k] = (float)vs16[base + (size_t)r * DH_ + d];
    }

#pragma unroll
    for (int it = 0; it < 16; it++) {
        int i = i0 + wv * 16 + it;
        float acc = 0.f;
        if (i >= 16 && i <= N_ - 17) {
#pragma unroll
            for (int o = -16; o <= 16; o++)
                acc += wt[o < 0 ? -o : o] * v[16 + it + o];
            acc *= inv_wfull;
        } else {
            float ws = 0.f;
#pragma unroll
            for (int o = -16; o <= 16; o++) {
                int j = i + o;
                if (j >= 0 && j <= N_ - 1) {
                    float w = wt[o < 0 ? -o : o];
                    ws += w;
                    acc += w * v[16 + it + o];
                }
            }
            acc /= ws;
        }
        cat[((size_t)(b * N_ + i)) * 1024 + h * 128 + 64 + d] = (f16)acc;
    }
}

// ---------------- launch ----------------

extern "C" void kernel_launch(void* const* d_in, const int* in_sizes, int n_in,
                              void* d_out, int out_size, void* d_ws, size_t ws_size,
                              hipStream_t stream) {
    const float* x      = (const float*)d_in[0];
    const float* w_qkvg = (const float*)d_in[1];
    const float* sigma  = (const float*)d_in[2];
    const float* w_out  = (const float*)d_in[3];
    const float* b_out  = (const float*)d_in[4];
    float* out = (float*)d_out;
    char* ws = (char*)d_ws;

    const size_t MB = 1048576;
    f16*   x16  = (f16*)(ws);                // 0-8 MB   (dead after gemm0)
    float* lacc = (float*)(ws);              // 0-0.5 MB (overlays dead x16; attn+)
    f16*   wqT  = (f16*)(ws + 8 * MB);       // 8-10
    f16*   woT  = (f16*)(ws + 10 * MB);      // 10-11
    f16*   qb   = (f16*)(ws + 11 * MB);      // 11-19
    f16*   kb   = (f16*)(ws + 19 * MB);      // 19-27
    f16*   vbT  = (f16*)(ws + 27 * MB);      // 27-35  [bh][dh][n]
    f16*   vs16 = (f16*)(ws + 35 * MB);      // 35-43  vsigma f16
    f16*   cat  = (f16*)(ws + 43 * MB);      // 43-59  [8192][1024]
    f16*   oaccB= (f16*)(ws + 59 * MB);      // 59-67  [32][2048][64]
    if (ws_size < 67 * MB) return;           // scratch guard

    cvt_f16_k8<<<2048, 256, 0, stream>>>(x, x16, B_ * N_ * DIM_ / 8);
    transpose_cvt_k<<<256, 256, 0, stream>>>(w_qkvg, wqT, 512, 2048);
    transpose_cvt_k<<<128, 256, 0, stream>>>(w_out, woT, 1024, 512);

    gemm_bt<0><<<dim3(16, 64), 256, 0, stream>>>(x16, wqT, 512, 2048,
                                                 qb, kb, vbT, vs16, nullptr, nullptr);

    attn_k<<<1024, 256, 0, stream>>>(qb, kb, vbT, cat, oaccB, lacc);
    combine_k<<<2048, 256, 0, stream>>>(cat, oaccB, lacc);
    gauss_k<<<dim3(32, 32), 256, 0, stream>>>(vs16, sigma, cat);

    gemm_small<<<dim3(8, 128), 256, 0, stream>>>(cat, woT, 1024, 512, b_out, out);
}

// Round 14
// 122.944 us; speedup vs baseline: 1.1106x; 1.0648x over previous
//
#include <hip/hip_runtime.h>

typedef _Float16 f16;
typedef __attribute__((ext_vector_type(8))) _Float16 f16x8;
typedef __attribute__((ext_vector_type(4))) _Float16 f16x4;
typedef __attribute__((ext_vector_type(4))) float f32x4;

#define B_ 4
#define N_ 2048
#define DIM_ 512
#define H_ 8
#define DH_ 64

// global -> LDS direct (16B per lane). LDS dest must be wave-uniform;
// global src is per-lane (pre-swizzled). Size must be literal 16.
__device__ __forceinline__ void gload16(const void* g, void* l) {
    __builtin_amdgcn_global_load_lds((const __attribute__((address_space(1))) void*)g,
                                     (__attribute__((address_space(3))) void*)l, 16, 0, 0);
}

// ---------------- small conversion kernels ----------------

__global__ __launch_bounds__(256) void cvt_f16_k8(const float* __restrict__ in,
                                                  f16* __restrict__ out, int n8) {
    int i = blockIdx.x * 256 + threadIdx.x;
    if (i < n8) {
        const float4 a = ((const float4*)in)[i * 2];
        const float4 b = ((const float4*)in)[i * 2 + 1];
        f16x8 o = {(f16)a.x, (f16)a.y, (f16)a.z, (f16)a.w,
                   (f16)b.x, (f16)b.y, (f16)b.z, (f16)b.w};
        ((f16x8*)out)[i] = o;
    }
}

// out[n*K + k] = (f16) in[k*N + n]; LDS-tiled 64x64, coalesced on both sides.
__global__ __launch_bounds__(256) void transpose_cvt_k(const float* __restrict__ in,
                                                       f16* __restrict__ out, int K, int N) {
    __shared__ f16 tile[64][72];            // [n][k], +8 pad
    const int nbk = K >> 6;
    const int bk = blockIdx.x % nbk, bn = blockIdx.x / nbk;
    const int k0 = bk << 6, n0 = bn << 6;
    const int t = threadIdx.x;
    const int r = t >> 2, q = (t & 3) << 4;
#pragma unroll
    for (int u = 0; u < 4; u++) {
        const float4 v = *(const float4*)&in[(size_t)(k0 + r) * N + n0 + q + u * 4];
        tile[q + u * 4 + 0][r] = (f16)v.x;
        tile[q + u * 4 + 1][r] = (f16)v.y;
        tile[q + u * 4 + 2][r] = (f16)v.z;
        tile[q + u * 4 + 3][r] = (f16)v.w;
    }
    __syncthreads();
#pragma unroll
    for (int u = 0; u < 2; u++) {
        f16x8 o = *(const f16x8*)&tile[r][q + u * 8];
        *(f16x8*)&out[(size_t)(n0 + r) * K + k0 + q + u * 8] = o;
    }
}

// ---------------- GEMM: C = A[M][K] * BT[N][K]^T (m97 structure) ----------------
// Flat grid 1024 with XCD-M-stripe mapping: xcd = bid&7 owns m-blocks
// [xcd*8, xcd*8+8) x all 16 n-blocks -> per-XCD A-stripe = 1MB (L2-fit),
// B = 2MB (L2-fit). Old dim3 grid round-robined n-blocks across XCDs, so
// every XCD re-read ALL of A (8x duplication from L3).
__global__ __launch_bounds__(256) void gemm_bt0(
    const f16* __restrict__ A, const f16* __restrict__ BT, int K, int N,
    f16* __restrict__ qb, f16* __restrict__ kb, f16* __restrict__ vbT,
    f16* __restrict__ vs16)
{
    __shared__ char sAb[16384];   // [128 m][64 k] f16, swizzled
    __shared__ char sBb[16384];   // [128 n][64 k] f16, swizzled
    const int tid = threadIdx.x;
    const int bid = blockIdx.x;                 // 1024
    const int xcd = bid & 7, w = bid >> 3;      // w in [0,128)
    const int m0 = ((xcd << 3) + (w >> 4)) << 7;   // 64 m-blocks of 128
    const int n0 = (w & 15) << 7;                  // 16 n-blocks of 128
    const int wave = tid >> 6, lane = tid & 63;
    const int wr = wave >> 1, wc = wave & 1;
    const int lr = lane & 15, lg = lane >> 4;

    f32x4 acc[4][4];
    const f32x4 zero = {0.f, 0.f, 0.f, 0.f};
#pragma unroll
    for (int i = 0; i < 4; i++)
#pragma unroll
        for (int j = 0; j < 4; j++) acc[i][j] = zero;

    const f16* srcA[4]; const f16* srcB[4];
    char* ldsA[4]; char* ldsB[4];
#pragma unroll
    for (int u = 0; u < 4; u++) {
        int row = wave * 8 + u * 32 + (lane >> 3);
        int e0 = ((lane & 7) ^ (row & 7)) << 3;
        srcA[u] = A + (size_t)(m0 + row) * K + e0;
        srcB[u] = BT + (size_t)(n0 + row) * K + e0;
        ldsA[u] = sAb + wave * 1024 + u * 4096;
        ldsB[u] = sBb + wave * 1024 + u * 4096;
    }

    const int swz = (lr & 7) << 4;
    for (int kt = 0; kt < K; kt += 64) {
#pragma unroll
        for (int u = 0; u < 4; u++) {
            gload16(srcA[u], ldsA[u]);
            gload16(srcB[u], ldsB[u]);
            srcA[u] += 64; srcB[u] += 64;
        }
        __syncthreads();
#pragma unroll
        for (int half = 0; half < 2; half++) {
            f16x8 af[4], bf[4];
#pragma unroll
            for (int i = 0; i < 4; i++) {
                int R = wr * 64 + i * 16 + lr;
                af[i] = *(const f16x8*)(sAb + R * 128 + (((half << 6) | (lg << 4)) ^ swz));
            }
#pragma unroll
            for (int j = 0; j < 4; j++) {
                int R = wc * 64 + j * 16 + lr;
                bf[j] = *(const f16x8*)(sBb + R * 128 + (((half << 6) | (lg << 4)) ^ swz));
            }
#pragma unroll
            for (int i = 0; i < 4; i++)
#pragma unroll
                for (int j = 0; j < 4; j++)
                    acc[i][j] = __builtin_amdgcn_mfma_f32_16x16x32_f16(af[i], bf[j], acc[i][j], 0, 0, 0);
        }
        __syncthreads();
    }

#pragma unroll
    for (int i = 0; i < 4; i++) {
#pragma unroll
        for (int j = 0; j < 4; j++) {
            int col = n0 + wc * 64 + j * 16 + lr;
            int row0 = m0 + wr * 64 + i * 16 + lg * 4;
            int sec = col >> 9, cc = col & 511;
            int h = cc >> 6, d = cc & 63;
            int b = row0 >> 11, ns = row0 & 2047;
            if (sec == 2) {
                f16x4 o;
#pragma unroll
                for (int r = 0; r < 4; r++) o[r] = (f16)acc[i][j][r];
                *(f16x4*)&vbT[((size_t)(b * H_ + h) * DH_ + d) * N_ + ns] = o;
            } else if (sec == 0) {
#pragma unroll
                for (int r = 0; r < 4; r++)
                    qb[((size_t)(b * H_ + h) * N_ + ns + r) * DH_ + d] = (f16)(acc[i][j][r] * 0.1803368801f);
            } else if (sec == 1) {
#pragma unroll
                for (int r = 0; r < 4; r++)
                    kb[((size_t)(b * H_ + h) * N_ + ns + r) * DH_ + d] = (f16)acc[i][j][r];
            } else {
#pragma unroll
                for (int r = 0; r < 4; r++)
                    vs16[((size_t)(b * H_ + h) * N_ + ns + r) * DH_ + d] = (f16)acc[i][j][r];
            }
        }
    }
}

// ---------------- small-N GEMM (final projection): 64x64 tile ----------------
// Flat grid 1024, XCD-M-stripe: xcd owns m-blocks [xcd*16, xcd*16+16) x all
// 8 n-blocks -> per-XCD A(cat)-stripe = 2MB (L2-fit) vs full 16MB before.
__global__ __launch_bounds__(256) void gemm_small(
    const f16* __restrict__ A, const f16* __restrict__ BT, int K, int N,
    const float* __restrict__ bias, float* __restrict__ outp)
{
    __shared__ char sAb[8192];
    __shared__ char sBb[8192];
    const int tid = threadIdx.x;
    const int bid = blockIdx.x;                 // 1024
    const int xcd = bid & 7, w = bid >> 3;      // w in [0,128)
    const int m0 = ((xcd << 4) + (w >> 3)) << 6;   // 128 m-blocks of 64
    const int n0 = (w & 7) << 6;                   // 8 n-blocks of 64
    const int wave = tid >> 6, lane = tid & 63;
    const int wr = wave >> 1, wc = wave & 1;
    const int lr = lane & 15, lg = lane >> 4;

    f32x4 acc[2][2];
    const f32x4 zero = {0.f, 0.f, 0.f, 0.f};
#pragma unroll
    for (int i = 0; i < 2; i++)
#pragma unroll
        for (int j = 0; j < 2; j++) acc[i][j] = zero;

    const f16* srcA[2]; const f16* srcB[2];
    char* ldsA[2]; char* ldsB[2];
#pragma unroll
    for (int u = 0; u < 2; u++) {
        int row = wave * 8 + u * 32 + (lane >> 3);
        int e0 = ((lane & 7) ^ (row & 7)) << 3;
        srcA[u] = A + (size_t)(m0 + row) * K + e0;
        srcB[u] = BT + (size_t)(n0 + row) * K + e0;
        ldsA[u] = sAb + wave * 1024 + u * 4096;
        ldsB[u] = sBb + wave * 1024 + u * 4096;
    }

    const int swz = (lr & 7) << 4;
    for (int kt = 0; kt < K; kt += 64) {
#pragma unroll
        for (int u = 0; u < 2; u++) {
            gload16(srcA[u], ldsA[u]);
            gload16(srcB[u], ldsB[u]);
            srcA[u] += 64; srcB[u] += 64;
        }
        __syncthreads();
#pragma unroll
        for (int half = 0; half < 2; half++) {
            f16x8 af[2], bf[2];
#pragma unroll
            for (int i = 0; i < 2; i++) {
                int R = wr * 32 + i * 16 + lr;
                af[i] = *(const f16x8*)(sAb + R * 128 + (((half << 6) | (lg << 4)) ^ swz));
            }
#pragma unroll
            for (int j = 0; j < 2; j++) {
                int R = wc * 32 + j * 16 + lr;
                bf[j] = *(const f16x8*)(sBb + R * 128 + (((half << 6) | (lg << 4)) ^ swz));
            }
#pragma unroll
            for (int i = 0; i < 2; i++)
#pragma unroll
                for (int j = 0; j < 2; j++)
                    acc[i][j] = __builtin_amdgcn_mfma_f32_16x16x32_f16(af[i], bf[j], acc[i][j], 0, 0, 0);
        }
        __syncthreads();
    }

#pragma unroll
    for (int i = 0; i < 2; i++)
#pragma unroll
        for (int j = 0; j < 2; j++) {
            int col = n0 + wc * 32 + j * 16 + lr;
            int row0 = m0 + wr * 32 + i * 16 + lg * 4;
#pragma unroll
            for (int r = 0; r < 4; r++)
                outp[(size_t)(row0 + r) * N + col] = acc[i][j][r] + bias[col];
        }
}

// ---------------- flash attention (softmax branch), KV-split ----------------
// Body = R12 (KV-split halves, pure-add combine, 4 waves x 32q, K=32 PV via
// kv-permuted contraction). R13: K-bufs 3->2 (LDS 40->32KB: removes any
// 4-blocks/CU LDS residency cap) and SAFE sync order — issue(t+1) ->
// compute(t) -> vmcnt(0) -> s_barrier. (Old order waited own-counter AFTER
// the barrier: formally racy on other waves' staged slices; counted vmcnt
// was perf-null anyway per R8.)
__global__ __launch_bounds__(256) void attn_k(
    const f16* __restrict__ qb, const f16* __restrict__ kb, const f16* __restrict__ vbT,
    f16* __restrict__ cat, f16* __restrict__ oaccB, float* __restrict__ lacc)
{
    __shared__ char sKbf[2 * 8192];   // K bufs, [64 kv][64 dh] f16, swizzled
    __shared__ char sVbf[2 * 8192];   // V bufs, [64 d ][64 kv] f16, swizzled
    const int tid = threadIdx.x;
    const int bid0 = blockIdx.x;
    const int obid = (bid0 & 7) * 128 + (bid0 >> 3);   // bijective XCD swizzle (1024 = 8*128)
    const int bh = obid >> 5, qblk = (obid >> 1) & 15, half = obid & 1;
    const int b = bh >> 3, h = bh & 7;
    const int hn = half << 4;                          // base kv tile of this half
    const int wave = tid >> 6, lane = tid & 63;
    const int lr = lane & 15, lg = lane >> 4;

    const size_t base = (size_t)bh * N_ * DH_;
    const int qrow_a = qblk * 128 + wave * 32 + lr;
    const int qrow_b = qrow_a + 16;
    const f16x8 qfa0 = *(const f16x8*)&qb[base + (size_t)qrow_a * DH_ + lg * 8];
    const f16x8 qfa1 = *(const f16x8*)&qb[base + (size_t)qrow_a * DH_ + 32 + lg * 8];
    const f16x8 qfb0 = *(const f16x8*)&qb[base + (size_t)qrow_b * DH_ + lg * 8];
    const f16x8 qfb1 = *(const f16x8*)&qb[base + (size_t)qrow_b * DH_ + 32 + lg * 8];

    // per-lane staging sources (pre-swizzled); kv tile T: K at +T*4096, V at +T*64
    const f16* kq[2]; const f16* vq[2];
#pragma unroll
    for (int u = 0; u < 2; u++) {
        int row = wave * 8 + u * 32 + (lane >> 3);
        int e0 = ((lane & 7) ^ (row & 7)) << 3;
        kq[u] = kb + base + (size_t)row * 64 + e0;
        vq[u] = vbT + base + (size_t)row * 2048 + e0;
    }
    char* const ldsKw = sKbf + wave * 1024;
    char* const ldsVw = sVbf + wave * 1024;

    f32x4 Ota[4], Otb[4], lacc_a, lacc_b;
    const f32x4 zero = {0.f, 0.f, 0.f, 0.f};
#pragma unroll
    for (int dt = 0; dt < 4; dt++) { Ota[dt] = zero; Otb[dt] = zero; }
    lacc_a = zero; lacc_b = zero;
    const f16x8 ones8 = {(f16)1.f, (f16)1.f, (f16)1.f, (f16)1.f,
                         (f16)1.f, (f16)1.f, (f16)1.f, (f16)1.f};

    const int swz = (lr & 7) << 4;

    // prologue: stage tile hn into buf 0; drain before first compute
#pragma unroll
    for (int u = 0; u < 2; u++) gload16(kq[u] + (size_t)hn * 4096, ldsKw + u * 4096);
#pragma unroll
    for (int u = 0; u < 2; u++) gload16(vq[u] + hn * 64, ldsVw + u * 4096);
    asm volatile("s_waitcnt vmcnt(0)" ::: "memory");
    __builtin_amdgcn_s_barrier();

    for (int t = 0; t < 16; t++) {
        {   // issue tile t+1 into the other buffers (fly during compute)
            const int tn = hn + ((t + 1) & 15);        // wrap: tail prefetch harmless
            char* vdst = ldsVw + ((t + 1) & 1) * 8192;
            char* kdst = ldsKw + ((t + 1) & 1) * 8192;
#pragma unroll
            for (int u = 0; u < 2; u++) gload16(vq[u] + tn * 64, vdst + u * 4096);
#pragma unroll
            for (int u = 0; u < 2; u++) gload16(kq[u] + (size_t)tn * 4096, kdst + u * 4096);
        }

        const char* Kb = sKbf + (t & 1) * 8192;
        const char* Vb = sVbf + (t & 1) * 8192;

        // ---- St = K·Q^T for both q-halves; K-frags read once ----
        f32x4 sta[4], stb[4];
        __builtin_amdgcn_s_setprio(1);
#pragma unroll
        for (int ct = 0; ct < 4; ct++) {
            int row = ct * 16 + lr;
            f16x8 kf0 = *(const f16x8*)(Kb + (((row << 7) | (lg << 4)) ^ swz));
            f16x8 kf1 = *(const f16x8*)(Kb + (((row << 7) | 64 | (lg << 4)) ^ swz));
            f32x4 sa = __builtin_amdgcn_mfma_f32_16x16x32_f16(kf0, qfa0, zero, 0, 0, 0);
            sta[ct]  = __builtin_amdgcn_mfma_f32_16x16x32_f16(kf1, qfa1, sa, 0, 0, 0);
            f32x4 sb = __builtin_amdgcn_mfma_f32_16x16x32_f16(kf0, qfb0, zero, 0, 0, 0);
            stb[ct]  = __builtin_amdgcn_mfma_f32_16x16x32_f16(kf1, qfb1, sb, 0, 0, 0);
        }
        __builtin_amdgcn_s_setprio(0);

        // ---- P = exp2(St) (static max), packed to f16 quads ----
        f16x4 ppa[4], ppb[4];
#pragma unroll
        for (int ct = 0; ct < 4; ct++)
#pragma unroll
            for (int r = 0; r < 4; r++) {
                ppa[ct][r] = (f16)__builtin_amdgcn_exp2f(sta[ct][r]);
                ppb[ct][r] = (f16)__builtin_amdgcn_exp2f(stb[ct][r]);
            }

        // ---- PV + l-sum on K=32 MFMAs (kv-permuted contraction) ----
        __builtin_amdgcn_s_setprio(1);
#pragma unroll
        for (int c = 0; c < 2; c++) {
            f16x8 bfa = __builtin_shufflevector(ppa[2 * c], ppa[2 * c + 1], 0, 1, 2, 3, 4, 5, 6, 7);
            f16x8 bfb = __builtin_shufflevector(ppb[2 * c], ppb[2 * c + 1], 0, 1, 2, 3, 4, 5, 6, 7);
            lacc_a = __builtin_amdgcn_mfma_f32_16x16x32_f16(ones8, bfa, lacc_a, 0, 0, 0);
            lacc_b = __builtin_amdgcn_mfma_f32_16x16x32_f16(ones8, bfb, lacc_b, 0, 0, 0);
#pragma unroll
            for (int dt = 0; dt < 4; dt++) {
                int row = dt * 16 + lr;
                f16x4 vlo = *(const f16x4*)(Vb + (((row << 7) | (c << 6) | (lg << 3)) ^ swz));
                f16x4 vhi = *(const f16x4*)(Vb + (((row << 7) | (c << 6) | 32 | (lg << 3)) ^ swz));
                f16x8 vf = __builtin_shufflevector(vlo, vhi, 0, 1, 2, 3, 4, 5, 6, 7);
                Ota[dt] = __builtin_amdgcn_mfma_f32_16x16x32_f16(vf, bfa, Ota[dt], 0, 0, 0);
                Otb[dt] = __builtin_amdgcn_mfma_f32_16x16x32_f16(vf, bfb, Otb[dt], 0, 0, 0);
            }
        }
        __builtin_amdgcn_s_setprio(0);

        // safe order: drain t+1's staged loads, THEN barrier gating next tile
        asm volatile("s_waitcnt vmcnt(0)" ::: "memory");
        __builtin_amdgcn_s_barrier();
    }

    // ---- epilogue: write RAW partial O (f16) + l (f32); combine_k finishes ----
#pragma unroll
    for (int dt = 0; dt < 4; dt++) {
        f16x4 oa, ob;
#pragma unroll
        for (int r = 0; r < 4; r++) {
            oa[r] = (f16)Ota[dt][r];
            ob[r] = (f16)Otb[dt][r];
        }
        if (half == 0) {
            *(f16x4*)&cat[((size_t)(b * N_ + qrow_a)) * 1024 + h * 128 + dt * 16 + lg * 4] = oa;
            *(f16x4*)&cat[((size_t)(b * N_ + qrow_b)) * 1024 + h * 128 + dt * 16 + lg * 4] = ob;
        } else {
            *(f16x4*)&oaccB[((size_t)(bh * N_ + qrow_a)) * 64 + dt * 16 + lg * 4] = oa;
            *(f16x4*)&oaccB[((size_t)(bh * N_ + qrow_b)) * 64 + dt * 16 + lg * 4] = ob;
        }
    }
    if (lg == 0) {   // every lane's lacc[0] = full row-sum for q = lr (ones-trick)
        lacc[half * (32 * N_) + bh * N_ + qrow_a] = lacc_a[0];
        lacc[half * (32 * N_) + bh * N_ + qrow_b] = lacc_b[0];
    }
}

// ---------------- combine: cat = (O_A + O_B) / (l_A + l_B) ----------------
__global__ __launch_bounds__(256) void combine_k(
    f16* __restrict__ cat, const f16* __restrict__ oaccB, const float* __restrict__ lacc)
{
    int gi = blockIdx.x * 256 + threadIdx.x;      // 524288 = 65536 rows x 8
    int row = gi >> 3, c8 = gi & 7;               // row over [bh][q]
    int bh = row >> 11, q = row & 2047;
    int b = bh >> 3, h = bh & 7;
    float inv = 1.0f / (lacc[row] + lacc[32 * N_ + row]);
    f16* cp = &cat[((size_t)(b * N_ + q)) * 1024 + h * 128 + c8 * 8];
    f16x8 a = *(const f16x8*)cp;
    f16x8 o2 = *(const f16x8*)&oaccB[(size_t)row * 64 + c8 * 8];
    f16x8 o;
#pragma unroll
    for (int i = 0; i < 8; i++) o[i] = (f16)(((float)a[i] + (float)o2[i]) * inv);
    *(f16x8*)cp = o;
}

// ---------------- Gaussian positional branch: normalized band conv ----------------
__global__ __launch_bounds__(256) void gauss_k(
    const f16* __restrict__ vs16, const float* __restrict__ sigma, f16* __restrict__ cat)
{
    const int tid = threadIdx.x;
    const int bh = blockIdx.y, b = bh >> 3, h = bh & 7;
    const int i0 = blockIdx.x * 64;
    const int wv = tid >> 6, d = tid & 63;
    const float sig = sigma[h];
    const float c = 0.72134752f / (sig * sig);   // log2(e)/(2 sig^2)

    float wt[17];
#pragma unroll
    for (int o = 0; o <= 16; o++) wt[o] = __builtin_amdgcn_exp2f(-(float)(o * o) * c);
    float wfull = wt[0];
#pragma unroll
    for (int o = 1; o <= 16; o++) wfull += 2.f * wt[o];
    const float inv_wfull = 1.0f / wfull;

    const size_t base = (size_t)bh * N_ * DH_;
    const int r0 = i0 + wv * 16 - 16;
    float v[48];
#pragma unroll
    for (int k = 0; k < 48; k++) {
        int r = r0 + k; r = r < 0 ? 0 : (r > N_ - 1 ? N_ - 1 : r);
        v[k] = (float)vs16[base + (size_t)r * DH_ + d];
    }

#pragma unroll
    for (int it = 0; it < 16; it++) {
        int i = i0 + wv * 16 + it;
        float acc = 0.f;
        if (i >= 16 && i <= N_ - 17) {
#pragma unroll
            for (int o = -16; o <= 16; o++)
                acc += wt[o < 0 ? -o : o] * v[16 + it + o];
            acc *= inv_wfull;
        } else {
            float ws = 0.f;
#pragma unroll
            for (int o = -16; o <= 16; o++) {
                int j = i + o;
                if (j >= 0 && j <= N_ - 1) {
                    float w = wt[o < 0 ? -o : o];
                    ws += w;
                    acc += w * v[16 + it + o];
                }
            }
            acc /= ws;
        }
        cat[((size_t)(b * N_ + i)) * 1024 + h * 128 + 64 + d] = (f16)acc;
    }
}

// ---------------- launch ----------------

extern "C" void kernel_launch(void* const* d_in, const int* in_sizes, int n_in,
                              void* d_out, int out_size, void* d_ws, size_t ws_size,
                              hipStream_t stream) {
    const float* x      = (const float*)d_in[0];
    const float* w_qkvg = (const float*)d_in[1];
    const float* sigma  = (const float*)d_in[2];
    const float* w_out  = (const float*)d_in[3];
    const float* b_out  = (const float*)d_in[4];
    float* out = (float*)d_out;
    char* ws = (char*)d_ws;

    const size_t MB = 1048576;
    f16*   x16  = (f16*)(ws);                // 0-8 MB   (dead after gemm0)
    float* lacc = (float*)(ws);              // 0-0.5 MB (overlays dead x16; attn+)
    f16*   wqT  = (f16*)(ws + 8 * MB);       // 8-10
    f16*   woT  = (f16*)(ws + 10 * MB);      // 10-11
    f16*   qb   = (f16*)(ws + 11 * MB);      // 11-19
    f16*   kb   = (f16*)(ws + 19 * MB);      // 19-27
    f16*   vbT  = (f16*)(ws + 27 * MB);      // 27-35  [bh][dh][n]
    f16*   vs16 = (f16*)(ws + 35 * MB);      // 35-43  vsigma f16
    f16*   cat  = (f16*)(ws + 43 * MB);      // 43-59  [8192][1024]
    f16*   oaccB= (f16*)(ws + 59 * MB);      // 59-67  [32][2048][64]
    if (ws_size < 67 * MB) return;           // scratch guard

    cvt_f16_k8<<<2048, 256, 0, stream>>>(x, x16, B_ * N_ * DIM_ / 8);
    transpose_cvt_k<<<256, 256, 0, stream>>>(w_qkvg, wqT, 512, 2048);
    transpose_cvt_k<<<128, 256, 0, stream>>>(w_out, woT, 1024, 512);

    gemm_bt0<<<1024, 256, 0, stream>>>(x16, wqT, 512, 2048, qb, kb, vbT, vs16);

    attn_k<<<1024, 256, 0, stream>>>(qb, kb, vbT, cat, oaccB, lacc);
    combine_k<<<2048, 256, 0, stream>>>(cat, oaccB, lacc);
    gauss_k<<<dim3(32, 32), 256, 0, stream>>>(vs16, sigma, cat);

    gemm_small<<<1024, 256, 0, stream>>>(cat, woT, 1024, 512, b_out, out);
}

// Round 15
// 120.793 us; speedup vs baseline: 1.1304x; 1.0178x over previous
//
#include <hip/hip_runtime.h>

typedef _Float16 f16;
typedef __attribute__((ext_vector_type(8))) _Float16 f16x8;
typedef __attribute__((ext_vector_type(4))) _Float16 f16x4;
typedef __attribute__((ext_vector_type(4))) float f32x4;

#define B_ 4
#define N_ 2048
#define DIM_ 512
#define H_ 8
#define DH_ 64

// global -> LDS direct (16B per lane). LDS dest must be wave-uniform;
// global src is per-lane (pre-swizzled). Size must be literal 16.
__device__ __forceinline__ void gload16(const void* g, void* l) {
    __builtin_amdgcn_global_load_lds((const __attribute__((address_space(1))) void*)g,
                                     (__attribute__((address_space(3))) void*)l, 16, 0, 0);
}

// ---------------- small conversion kernels ----------------

__global__ __launch_bounds__(256) void cvt_f16_k8(const float* __restrict__ in,
                                                  f16* __restrict__ out, int n8) {
    int i = blockIdx.x * 256 + threadIdx.x;
    if (i < n8) {
        const float4 a = ((const float4*)in)[i * 2];
        const float4 b = ((const float4*)in)[i * 2 + 1];
        f16x8 o = {(f16)a.x, (f16)a.y, (f16)a.z, (f16)a.w,
                   (f16)b.x, (f16)b.y, (f16)b.z, (f16)b.w};
        ((f16x8*)out)[i] = o;
    }
}

// out[n*K + k] = (f16) in[k*N + n]; LDS-tiled 64x64, coalesced on both sides.
__global__ __launch_bounds__(256) void transpose_cvt_k(const float* __restrict__ in,
                                                       f16* __restrict__ out, int K, int N) {
    __shared__ f16 tile[64][72];            // [n][k], +8 pad
    const int nbk = K >> 6;
    const int bk = blockIdx.x % nbk, bn = blockIdx.x / nbk;
    const int k0 = bk << 6, n0 = bn << 6;
    const int t = threadIdx.x;
    const int r = t >> 2, q = (t & 3) << 4;
#pragma unroll
    for (int u = 0; u < 4; u++) {
        const float4 v = *(const float4*)&in[(size_t)(k0 + r) * N + n0 + q + u * 4];
        tile[q + u * 4 + 0][r] = (f16)v.x;
        tile[q + u * 4 + 1][r] = (f16)v.y;
        tile[q + u * 4 + 2][r] = (f16)v.z;
        tile[q + u * 4 + 3][r] = (f16)v.w;
    }
    __syncthreads();
#pragma unroll
    for (int u = 0; u < 2; u++) {
        f16x8 o = *(const f16x8*)&tile[r][q + u * 8];
        *(f16x8*)&out[(size_t)(n0 + r) * K + k0 + q + u * 8] = o;
    }
}

// ---------------- qkvg GEMM: 8-phase 256x256 template (T2+T3+T4+T5) ----------------
// M=8192,N=2048,K=512. 512 thr = 8 waves (2M x 4N); per-wave out 128x64.
// LDS 128KB: A halves [128][64]f16 at (d*2+h)*16K; B at +64K. 2 K-tile dbufs.
// Per K-tile: 4 phases {stage 1 half-tile of T+1 -> [ph0: vmcnt(2)] -> barrier
// -> 8 ds_read_b128 -> lgkmcnt(0) -> 16 MFMA (setprio) -> barrier}.
// vmcnt ledger: T's 8 loads issued during T-1's phases; at T-ph0 exactly 2
// newer are outstanding -> vmcnt(2), never 0 (loads span barriers = T4).
// Race safety: stages target dbuf (T+1)&1, last read before T-1/ph3's trailing
// barrier; ph0's leading barrier is after ALL waves' vmcnt -> cross-wave
// staged chunks landed before any ds_read. Swizzle: slot s of row r holds
// global slot s^(r&7) (involution, both sides).
__global__ __launch_bounds__(512, 2) void gemm0_8ph(
    const f16* __restrict__ A, const f16* __restrict__ BT,
    f16* __restrict__ qb, f16* __restrict__ kb, f16* __restrict__ vbT,
    f16* __restrict__ vs16)
{
    __shared__ char lds[131072];
    const int tid = threadIdx.x;
    const int bid = blockIdx.x;                 // 256 blocks = 1/CU
    const int xcd = bid & 7, w = bid >> 3;      // w in [0,32)
    const int m0 = ((xcd << 2) + (w >> 3)) << 8;   // 32 m-blocks of 256
    const int n0 = (w & 7) << 8;                   // 8 n-blocks of 256
    const int wave = tid >> 6, lane = tid & 63;
    const int wr = wave >> 2, wc = wave & 3;       // 2M x 4N wave grid
    const int lr = lane & 15, lg = lane >> 4;

    f32x4 acc[8][4];
    const f32x4 zero = {0.f, 0.f, 0.f, 0.f};
#pragma unroll
    for (int i = 0; i < 8; i++)
#pragma unroll
        for (int j = 0; j < 4; j++) acc[i][j] = zero;

    // staging geometry: chunk c = tid + u*512 covers half-tile [128][64]f16;
    // row = c>>3, slot = c&7, pre-swizzled source slot = (c&7)^(row&7).
    const f16* gA[2][2]; const f16* gB[2][2];   // [half][u]
#pragma unroll
    for (int u = 0; u < 2; u++) {
        int c = tid + u * 512;
        int row = c >> 3;
        int e0 = (((c & 7) ^ (row & 7)) << 3);
#pragma unroll
        for (int h = 0; h < 2; h++) {
            gA[h][u] = A + (size_t)(m0 + h * 128 + row) * 512 + e0;
            gB[h][u] = BT + (size_t)(n0 + h * 128 + row) * 512 + e0;
        }
    }
    const int ldst = wave * 1024;               // + u*8192 + lane*16 (HW)

    // prologue: stage K-tile 0 into dbuf 0 (A0,A1,B0,B1 = 8 loads)
#pragma unroll
    for (int h = 0; h < 2; h++)
#pragma unroll
        for (int u = 0; u < 2; u++)
            gload16(gA[h][u], lds + h * 16384 + ldst + u * 8192);
#pragma unroll
    for (int h = 0; h < 2; h++)
#pragma unroll
        for (int u = 0; u < 2; u++)
            gload16(gB[h][u], lds + 65536 + h * 16384 + ldst + u * 8192);

    const int swz = (lr & 7) << 4;
    for (int T = 0; T < 8; T++) {
        const int d = T & 1, d2 = (T + 1) & 1;
        const size_t Tn64 = (size_t)(T + 1) * 64;   // T=7 prefetch overruns into
                                                    // adjacent ws (mapped, dummy)
        const char* Ab = lds + (d * 2 + wr) * 16384;
        const char* Bb = lds + 65536 + (d * 2 + (wc >> 1)) * 16384;
#pragma unroll
        for (int p = 0; p < 4; p++) {
            const int kh = p >> 1, qr = p & 1;
            // stage half-tile p of K-tile T+1 into dbuf d2
            if (p < 2) {
#pragma unroll
                for (int u = 0; u < 2; u++)
                    gload16(gA[p][u] + Tn64, lds + (d2 * 2 + p) * 16384 + ldst + u * 8192);
            } else {
#pragma unroll
                for (int u = 0; u < 2; u++)
                    gload16(gB[p - 2][u] + Tn64, lds + 65536 + (d2 * 2 + (p - 2)) * 16384 + ldst + u * 8192);
            }
            if (p == 0) {
                asm volatile("s_waitcnt vmcnt(2)" ::: "memory");   // T landed; 2 in flight
            }
            __builtin_amdgcn_s_barrier();       // all waves' vmcnt passed -> T valid

            f16x8 af[4], bf[4];
            const int ko = (kh * 64 + lg * 16) ^ swz;
#pragma unroll
            for (int i = 0; i < 4; i++)
                af[i] = *(const f16x8*)(Ab + (qr * 64 + i * 16 + lr) * 128 + ko);
#pragma unroll
            for (int j = 0; j < 4; j++)
                bf[j] = *(const f16x8*)(Bb + ((wc & 1) * 64 + j * 16 + lr) * 128 + ko);
            asm volatile("s_waitcnt lgkmcnt(0)" ::: "memory");
            __builtin_amdgcn_sched_barrier(0);
            __builtin_amdgcn_s_setprio(1);
#pragma unroll
            for (int i = 0; i < 4; i++)
#pragma unroll
                for (int j = 0; j < 4; j++)
                    acc[qr * 4 + i][j] = __builtin_amdgcn_mfma_f32_16x16x32_f16(af[i], bf[j], acc[qr * 4 + i][j], 0, 0, 0);
            __builtin_amdgcn_s_setprio(0);
            __builtin_amdgcn_s_barrier();       // readers done before next stage into d
        }
    }

    // epilogue: route qkvg columns (q scaled to exp2 domain, V transposed)
#pragma unroll
    for (int fr = 0; fr < 8; fr++) {
#pragma unroll
        for (int j = 0; j < 4; j++) {
            int col = n0 + wc * 64 + j * 16 + lr;
            int row0 = m0 + wr * 128 + fr * 16 + lg * 4;
            int sec = col >> 9, cc = col & 511;
            int h = cc >> 6, dd = cc & 63;
            int b = row0 >> 11, ns = row0 & 2047;
            if (sec == 2) {
                f16x4 o;
#pragma unroll
                for (int r = 0; r < 4; r++) o[r] = (f16)acc[fr][j][r];
                *(f16x4*)&vbT[((size_t)(b * H_ + h) * DH_ + dd) * N_ + ns] = o;
            } else if (sec == 0) {
#pragma unroll
                for (int r = 0; r < 4; r++)
                    qb[((size_t)(b * H_ + h) * N_ + ns + r) * DH_ + dd] = (f16)(acc[fr][j][r] * 0.1803368801f);
            } else if (sec == 1) {
#pragma unroll
                for (int r = 0; r < 4; r++)
                    kb[((size_t)(b * H_ + h) * N_ + ns + r) * DH_ + dd] = (f16)acc[fr][j][r];
            } else {
#pragma unroll
                for (int r = 0; r < 4; r++)
                    vs16[((size_t)(b * H_ + h) * N_ + ns + r) * DH_ + dd] = (f16)acc[fr][j][r];
            }
        }
    }
}

// ---------------- small-N GEMM (final projection): 64x64 tile ----------------
// Flat grid 1024, XCD-M-stripe: per-XCD A(cat)-stripe = 2MB (L2-fit).
__global__ __launch_bounds__(256) void gemm_small(
    const f16* __restrict__ A, const f16* __restrict__ BT, int K, int N,
    const float* __restrict__ bias, float* __restrict__ outp)
{
    __shared__ char sAb[8192];
    __shared__ char sBb[8192];
    const int tid = threadIdx.x;
    const int bid = blockIdx.x;                 // 1024
    const int xcd = bid & 7, w = bid >> 3;      // w in [0,128)
    const int m0 = ((xcd << 4) + (w >> 3)) << 6;   // 128 m-blocks of 64
    const int n0 = (w & 7) << 6;                   // 8 n-blocks of 64
    const int wave = tid >> 6, lane = tid & 63;
    const int wr = wave >> 1, wc = wave & 1;
    const int lr = lane & 15, lg = lane >> 4;

    f32x4 acc[2][2];
    const f32x4 zero = {0.f, 0.f, 0.f, 0.f};
#pragma unroll
    for (int i = 0; i < 2; i++)
#pragma unroll
        for (int j = 0; j < 2; j++) acc[i][j] = zero;

    const f16* srcA[2]; const f16* srcB[2];
    char* ldsA[2]; char* ldsB[2];
#pragma unroll
    for (int u = 0; u < 2; u++) {
        int row = wave * 8 + u * 32 + (lane >> 3);
        int e0 = ((lane & 7) ^ (row & 7)) << 3;
        srcA[u] = A + (size_t)(m0 + row) * K + e0;
        srcB[u] = BT + (size_t)(n0 + row) * K + e0;
        ldsA[u] = sAb + wave * 1024 + u * 4096;
        ldsB[u] = sBb + wave * 1024 + u * 4096;
    }

    const int swz = (lr & 7) << 4;
    for (int kt = 0; kt < K; kt += 64) {
#pragma unroll
        for (int u = 0; u < 2; u++) {
            gload16(srcA[u], ldsA[u]);
            gload16(srcB[u], ldsB[u]);
            srcA[u] += 64; srcB[u] += 64;
        }
        __syncthreads();
#pragma unroll
        for (int half = 0; half < 2; half++) {
            f16x8 af[2], bf[2];
#pragma unroll
            for (int i = 0; i < 2; i++) {
                int R = wr * 32 + i * 16 + lr;
                af[i] = *(const f16x8*)(sAb + R * 128 + (((half << 6) | (lg << 4)) ^ swz));
            }
#pragma unroll
            for (int j = 0; j < 2; j++) {
                int R = wc * 32 + j * 16 + lr;
                bf[j] = *(const f16x8*)(sBb + R * 128 + (((half << 6) | (lg << 4)) ^ swz));
            }
#pragma unroll
            for (int i = 0; i < 2; i++)
#pragma unroll
                for (int j = 0; j < 2; j++)
                    acc[i][j] = __builtin_amdgcn_mfma_f32_16x16x32_f16(af[i], bf[j], acc[i][j], 0, 0, 0);
        }
        __syncthreads();
    }

#pragma unroll
    for (int i = 0; i < 2; i++)
#pragma unroll
        for (int j = 0; j < 2; j++) {
            int col = n0 + wc * 32 + j * 16 + lr;
            int row0 = m0 + wr * 32 + i * 16 + lg * 4;
#pragma unroll
            for (int r = 0; r < 4; r++)
                outp[(size_t)(row0 + r) * N + col] = acc[i][j][r] + bias[col];
        }
}

// ---------------- flash attention (softmax branch), KV-split (R13) ----------------
__global__ __launch_bounds__(256) void attn_k(
    const f16* __restrict__ qb, const f16* __restrict__ kb, const f16* __restrict__ vbT,
    f16* __restrict__ cat, f16* __restrict__ oaccB, float* __restrict__ lacc)
{
    __shared__ char sKbf[2 * 8192];   // K bufs, [64 kv][64 dh] f16, swizzled
    __shared__ char sVbf[2 * 8192];   // V bufs, [64 d ][64 kv] f16, swizzled
    const int tid = threadIdx.x;
    const int bid0 = blockIdx.x;
    const int obid = (bid0 & 7) * 128 + (bid0 >> 3);   // bijective XCD swizzle (1024 = 8*128)
    const int bh = obid >> 5, qblk = (obid >> 1) & 15, half = obid & 1;
    const int b = bh >> 3, h = bh & 7;
    const int hn = half << 4;                          // base kv tile of this half
    const int wave = tid >> 6, lane = tid & 63;
    const int lr = lane & 15, lg = lane >> 4;

    const size_t base = (size_t)bh * N_ * DH_;
    const int qrow_a = qblk * 128 + wave * 32 + lr;
    const int qrow_b = qrow_a + 16;
    const f16x8 qfa0 = *(const f16x8*)&qb[base + (size_t)qrow_a * DH_ + lg * 8];
    const f16x8 qfa1 = *(const f16x8*)&qb[base + (size_t)qrow_a * DH_ + 32 + lg * 8];
    const f16x8 qfb0 = *(const f16x8*)&qb[base + (size_t)qrow_b * DH_ + lg * 8];
    const f16x8 qfb1 = *(const f16x8*)&qb[base + (size_t)qrow_b * DH_ + 32 + lg * 8];

    const f16* kq[2]; const f16* vq[2];
#pragma unroll
    for (int u = 0; u < 2; u++) {
        int row = wave * 8 + u * 32 + (lane >> 3);
        int e0 = ((lane & 7) ^ (row & 7)) << 3;
        kq[u] = kb + base + (size_t)row * 64 + e0;
        vq[u] = vbT + base + (size_t)row * 2048 + e0;
    }
    char* const ldsKw = sKbf + wave * 1024;
    char* const ldsVw = sVbf + wave * 1024;

    f32x4 Ota[4], Otb[4], lacc_a, lacc_b;
    const f32x4 zero = {0.f, 0.f, 0.f, 0.f};
#pragma unroll
    for (int dt = 0; dt < 4; dt++) { Ota[dt] = zero; Otb[dt] = zero; }
    lacc_a = zero; lacc_b = zero;
    const f16x8 ones8 = {(f16)1.f, (f16)1.f, (f16)1.f, (f16)1.f,
                         (f16)1.f, (f16)1.f, (f16)1.f, (f16)1.f};

    const int swz = (lr & 7) << 4;

    // prologue: stage tile hn into buf 0; drain before first compute
#pragma unroll
    for (int u = 0; u < 2; u++) gload16(kq[u] + (size_t)hn * 4096, ldsKw + u * 4096);
#pragma unroll
    for (int u = 0; u < 2; u++) gload16(vq[u] + hn * 64, ldsVw + u * 4096);
    asm volatile("s_waitcnt vmcnt(0)" ::: "memory");
    __builtin_amdgcn_s_barrier();

    for (int t = 0; t < 16; t++) {
        {   // issue tile t+1 into the other buffers (fly during compute)
            const int tn = hn + ((t + 1) & 15);
            char* vdst = ldsVw + ((t + 1) & 1) * 8192;
            char* kdst = ldsKw + ((t + 1) & 1) * 8192;
#pragma unroll
            for (int u = 0; u < 2; u++) gload16(vq[u] + tn * 64, vdst + u * 4096);
#pragma unroll
            for (int u = 0; u < 2; u++) gload16(kq[u] + (size_t)tn * 4096, kdst + u * 4096);
        }

        const char* Kb = sKbf + (t & 1) * 8192;
        const char* Vb = sVbf + (t & 1) * 8192;

        f32x4 sta[4], stb[4];
        __builtin_amdgcn_s_setprio(1);
#pragma unroll
        for (int ct = 0; ct < 4; ct++) {
            int row = ct * 16 + lr;
            f16x8 kf0 = *(const f16x8*)(Kb + (((row << 7) | (lg << 4)) ^ swz));
            f16x8 kf1 = *(const f16x8*)(Kb + (((row << 7) | 64 | (lg << 4)) ^ swz));
            f32x4 sa = __builtin_amdgcn_mfma_f32_16x16x32_f16(kf0, qfa0, zero, 0, 0, 0);
            sta[ct]  = __builtin_amdgcn_mfma_f32_16x16x32_f16(kf1, qfa1, sa, 0, 0, 0);
            f32x4 sb = __builtin_amdgcn_mfma_f32_16x16x32_f16(kf0, qfb0, zero, 0, 0, 0);
            stb[ct]  = __builtin_amdgcn_mfma_f32_16x16x32_f16(kf1, qfb1, sb, 0, 0, 0);
        }
        __builtin_amdgcn_s_setprio(0);

        f16x4 ppa[4], ppb[4];
#pragma unroll
        for (int ct = 0; ct < 4; ct++)
#pragma unroll
            for (int r = 0; r < 4; r++) {
                ppa[ct][r] = (f16)__builtin_amdgcn_exp2f(sta[ct][r]);
                ppb[ct][r] = (f16)__builtin_amdgcn_exp2f(stb[ct][r]);
            }

        __builtin_amdgcn_s_setprio(1);
#pragma unroll
        for (int c = 0; c < 2; c++) {
            f16x8 bfa = __builtin_shufflevector(ppa[2 * c], ppa[2 * c + 1], 0, 1, 2, 3, 4, 5, 6, 7);
            f16x8 bfb = __builtin_shufflevector(ppb[2 * c], ppb[2 * c + 1], 0, 1, 2, 3, 4, 5, 6, 7);
            lacc_a = __builtin_amdgcn_mfma_f32_16x16x32_f16(ones8, bfa, lacc_a, 0, 0, 0);
            lacc_b = __builtin_amdgcn_mfma_f32_16x16x32_f16(ones8, bfb, lacc_b, 0, 0, 0);
#pragma unroll
            for (int dt = 0; dt < 4; dt++) {
                int row = dt * 16 + lr;
                f16x4 vlo = *(const f16x4*)(Vb + (((row << 7) | (c << 6) | (lg << 3)) ^ swz));
                f16x4 vhi = *(const f16x4*)(Vb + (((row << 7) | (c << 6) | 32 | (lg << 3)) ^ swz));
                f16x8 vf = __builtin_shufflevector(vlo, vhi, 0, 1, 2, 3, 4, 5, 6, 7);
                Ota[dt] = __builtin_amdgcn_mfma_f32_16x16x32_f16(vf, bfa, Ota[dt], 0, 0, 0);
                Otb[dt] = __builtin_amdgcn_mfma_f32_16x16x32_f16(vf, bfb, Otb[dt], 0, 0, 0);
            }
        }
        __builtin_amdgcn_s_setprio(0);

        asm volatile("s_waitcnt vmcnt(0)" ::: "memory");
        __builtin_amdgcn_s_barrier();
    }

#pragma unroll
    for (int dt = 0; dt < 4; dt++) {
        f16x4 oa, ob;
#pragma unroll
        for (int r = 0; r < 4; r++) {
            oa[r] = (f16)Ota[dt][r];
            ob[r] = (f16)Otb[dt][r];
        }
        if (half == 0) {
            *(f16x4*)&cat[((size_t)(b * N_ + qrow_a)) * 1024 + h * 128 + dt * 16 + lg * 4] = oa;
            *(f16x4*)&cat[((size_t)(b * N_ + qrow_b)) * 1024 + h * 128 + dt * 16 + lg * 4] = ob;
        } else {
            *(f16x4*)&oaccB[((size_t)(bh * N_ + qrow_a)) * 64 + dt * 16 + lg * 4] = oa;
            *(f16x4*)&oaccB[((size_t)(bh * N_ + qrow_b)) * 64 + dt * 16 + lg * 4] = ob;
        }
    }
    if (lg == 0) {
        lacc[half * (32 * N_) + bh * N_ + qrow_a] = lacc_a[0];
        lacc[half * (32 * N_) + bh * N_ + qrow_b] = lacc_b[0];
    }
}

// ---------------- combine: cat = (O_A + O_B) / (l_A + l_B) ----------------
__global__ __launch_bounds__(256) void combine_k(
    f16* __restrict__ cat, const f16* __restrict__ oaccB, const float* __restrict__ lacc)
{
    int gi = blockIdx.x * 256 + threadIdx.x;      // 524288 = 65536 rows x 8
    int row = gi >> 3, c8 = gi & 7;
    int bh = row >> 11, q = row & 2047;
    int b = bh >> 3, h = bh & 7;
    float inv = 1.0f / (lacc[row] + lacc[32 * N_ + row]);
    f16* cp = &cat[((size_t)(b * N_ + q)) * 1024 + h * 128 + c8 * 8];
    f16x8 a = *(const f16x8*)cp;
    f16x8 o2 = *(const f16x8*)&oaccB[(size_t)row * 64 + c8 * 8];
    f16x8 o;
#pragma unroll
    for (int i = 0; i < 8; i++) o[i] = (f16)(((float)a[i] + (float)o2[i]) * inv);
    *(f16x8*)cp = o;
}

// ---------------- Gaussian positional branch: normalized band conv ----------------
__global__ __launch_bounds__(256) void gauss_k(
    const f16* __restrict__ vs16, const float* __restrict__ sigma, f16* __restrict__ cat)
{
    const int tid = threadIdx.x;
    const int bh = blockIdx.y, b = bh >> 3, h = bh & 7;
    const int i0 = blockIdx.x * 64;
    const int wv = tid >> 6, d = tid & 63;
    const float sig = sigma[h];
    const float c = 0.72134752f / (sig * sig);   // log2(e)/(2 sig^2)

    float wt[17];
#pragma unroll
    for (int o = 0; o <= 16; o++) wt[o] = __builtin_amdgcn_exp2f(-(float)(o * o) * c);
    float wfull = wt[0];
#pragma unroll
    for (int o = 1; o <= 16; o++) wfull += 2.f * wt[o];
    const float inv_wfull = 1.0f / wfull;

    const size_t base = (size_t)bh * N_ * DH_;
    const int r0 = i0 + wv * 16 - 16;
    float v[48];
#pragma unroll
    for (int k = 0; k < 48; k++) {
        int r = r0 + k; r = r < 0 ? 0 : (r > N_ - 1 ? N_ - 1 : r);
        v[k] = (float)vs16[base + (size_t)r * DH_ + d];
    }

#pragma unroll
    for (int it = 0; it < 16; it++) {
        int i = i0 + wv * 16 + it;
        float acc = 0.f;
        if (i >= 16 && i <= N_ - 17) {
#pragma unroll
            for (int o = -16; o <= 16; o++)
                acc += wt[o < 0 ? -o : o] * v[16 + it + o];
            acc *= inv_wfull;
        } else {
            float ws = 0.f;
#pragma unroll
            for (int o = -16; o <= 16; o++) {
                int j = i + o;
                if (j >= 0 && j <= N_ - 1) {
                    float w = wt[o < 0 ? -o : o];
                    ws += w;
                    acc += w * v[16 + it + o];
                }
            }
            acc /= ws;
        }
        cat[((size_t)(b * N_ + i)) * 1024 + h * 128 + 64 + d] = (f16)acc;
    }
}

// ---------------- launch ----------------

extern "C" void kernel_launch(void* const* d_in, const int* in_sizes, int n_in,
                              void* d_out, int out_size, void* d_ws, size_t ws_size,
                              hipStream_t stream) {
    const float* x      = (const float*)d_in[0];
    const float* w_qkvg = (const float*)d_in[1];
    const float* sigma  = (const float*)d_in[2];
    const float* w_out  = (const float*)d_in[3];
    const float* b_out  = (const float*)d_in[4];
    float* out = (float*)d_out;
    char* ws = (char*)d_ws;

    const size_t MB = 1048576;
    f16*   x16  = (f16*)(ws);                // 0-8 MB   (dead after gemm0)
    float* lacc = (float*)(ws);              // 0-0.5 MB (overlays dead x16; attn+)
    f16*   wqT  = (f16*)(ws + 8 * MB);       // 8-10
    f16*   woT  = (f16*)(ws + 10 * MB);      // 10-11
    f16*   qb   = (f16*)(ws + 11 * MB);      // 11-19
    f16*   kb   = (f16*)(ws + 19 * MB);      // 19-27
    f16*   vbT  = (f16*)(ws + 27 * MB);      // 27-35  [bh][dh][n]
    f16*   vs16 = (f16*)(ws + 35 * MB);      // 35-43  vsigma f16
    f16*   cat  = (f16*)(ws + 43 * MB);      // 43-59  [8192][1024]
    f16*   oaccB= (f16*)(ws + 59 * MB);      // 59-67  [32][2048][64]
    if (ws_size < 67 * MB) return;           // scratch guard

    cvt_f16_k8<<<2048, 256, 0, stream>>>(x, x16, B_ * N_ * DIM_ / 8);
    transpose_cvt_k<<<256, 256, 0, stream>>>(w_qkvg, wqT, 512, 2048);
    transpose_cvt_k<<<128, 256, 0, stream>>>(w_out, woT, 1024, 512);

    gemm0_8ph<<<256, 512, 0, stream>>>(x16, wqT, qb, kb, vbT, vs16);

    attn_k<<<1024, 256, 0, stream>>>(qb, kb, vbT, cat, oaccB, lacc);
    combine_k<<<2048, 256, 0, stream>>>(cat, oaccB, lacc);
    gauss_k<<<dim3(32, 32), 256, 0, stream>>>(vs16, sigma, cat);

    gemm_small<<<1024, 256, 0, stream>>>(cat, woT, 1024, 512, b_out, out);
}